// Round 9
// baseline (435.101 us; speedup 1.0000x reference)
//
#include <hip/hip_runtime.h>
#include <stdint.h>

typedef unsigned int u32;
typedef unsigned long long u64;

#define F_UPPER 0.4f
#define F_LOWER 0.1f
#define MAX_POS 2048
#define L_SZ 65536
#define M_SZ 512
#define C_SZ 21
#define NBINS 8192
#define BIN_CAP 32
#define OVF_CAP 1024
#define FLG_AGG (1ull << 62)
#define FLG_MASK (3ull << 62)

struct State {
  double sum_pos_ce;
  double sum_neg_ce;
  double bbox_sum;
  int num_pos;
  int num_neg;
  u32 done;
  u32 barrier;
  u64 thresh;
};

__device__ __forceinline__ float area_fn(const float4 a) {
#pragma clang fp contract(off)
  return (a.z - a.x + 1.0f) * (a.w - a.y + 1.0f);
}

// IoU, op order identical to prior rounds (absmax 0 preserved).
__device__ __forceinline__ float iou_rcp(const float4 a, const float4 b, float a1, float a2) {
#pragma clang fp contract(off)
  float iw = fminf(a.z, b.z) - fmaxf(a.x, b.x) + 1.0f;
  iw = fmaxf(iw, 0.0f);
  float ih = fminf(a.w, b.w) - fmaxf(a.y, b.y) + 1.0f;
  ih = fmaxf(ih, 0.0f);
  float inter = iw * ih;
  return inter * __builtin_amdgcn_rcpf(a1 + a2 - inter);
}

__device__ __forceinline__ float sl1(float d) {
#pragma clang fp contract(off)
  float ad = fabsf(d);
  return (ad < 0.01f) ? (50.0f * d * d) : (ad - 0.005f);
}

__device__ __forceinline__ u32 rotl(u32 x, int d) { return (x << d) | (x >> (32 - d)); }

// JAX threefry2x32, key=(0,42); counts = iota(L) split in halves.
__device__ u32 threefry_bits(u32 i, u32 H) {
  u32 x0, x1; bool hi;
  if (i < H) { x0 = i;     x1 = i + H; hi = false; }
  else       { x0 = i - H; x1 = i;     hi = true;  }
  const u32 ks0 = 0u, ks1 = 42u;
  const u32 ks2 = ks0 ^ ks1 ^ 0x1BD11BDAu;
  x0 += ks0; x1 += ks1;
#define RND(r) { x0 += x1; x1 = rotl(x1, r); x1 ^= x0; }
  RND(13) RND(15) RND(26) RND(6)   x0 += ks1; x1 += ks2 + 1u;
  RND(17) RND(29) RND(16) RND(24)  x0 += ks2; x1 += ks0 + 2u;
  RND(13) RND(15) RND(26) RND(6)   x0 += ks0; x1 += ks1 + 3u;
  RND(17) RND(29) RND(16) RND(24)  x0 += ks1; x1 += ks2 + 4u;
  RND(13) RND(15) RND(26) RND(6)   x0 += ks2; x1 += ks0 + 5u;
#undef RND
  return hi ? x1 : x0;
}

// Device-scope atomic loads (cross-XCD visibility, guide §6 G16).
__device__ __forceinline__ u32 ald32(const u32* p) {
  return __hip_atomic_load(p, __ATOMIC_ACQUIRE, __HIP_MEMORY_SCOPE_AGENT);
}
__device__ __forceinline__ u64 ald64(const u64* p) {
  return __hip_atomic_load(p, __ATOMIC_ACQUIRE, __HIP_MEMORY_SCOPE_AGENT);
}
__device__ __forceinline__ int aldi(const int* p) {
  return __hip_atomic_load(p, __ATOMIC_ACQUIRE, __HIP_MEMORY_SCOPE_AGENT);
}
__device__ __forceinline__ double aldd(const double* p) {
  return __hip_atomic_load(p, __ATOMIC_ACQUIRE, __HIP_MEMORY_SCOPE_AGENT);
}

// ======== kA: ROI + single-pass register-microtiled IoU. 1024 blocks, 64 preds/block.
// Micro-tile: pg = tid&7 owns preds 8*pg..+7 (boxes in VGPRs); gg = tid>>3 owns 16 gts.
// Per thread: 16 iters x (1 ds_read_b128 + 1 ds_read_b32 + 8 IoU evals + 1 ds u64 atomic).
__global__ void __launch_bounds__(256) kA(const float* __restrict__ rois,
    const float* __restrict__ scores, const float* __restrict__ deltas,
    const float4* __restrict__ gtb,
    float4* __restrict__ pred, float* __restrict__ lse,
    u64* __restrict__ rowkey, u64* __restrict__ gkey) {
  __shared__ float  ssc[64 * C_SZ];
  __shared__ float  sro[64 * 5];
  __shared__ float4 sg[M_SZ];
  __shared__ float  ga[M_SZ];
  __shared__ u64    scol[M_SZ];
  __shared__ u64    srow[64];
  __shared__ float4 spred[64];
  __shared__ float  sarea[64];
  const int tid = threadIdx.x;
  const int pbase = blockIdx.x << 6;
  for (int k = tid; k < 64 * C_SZ; k += 256) ssc[k] = scores[(size_t)pbase * C_SZ + k];
  for (int k = tid; k < 64 * 5; k += 256)    sro[k] = rois[(size_t)pbase * 5 + k];
  for (int j = tid; j < M_SZ; j += 256) {
    float4 g = gtb[j]; sg[j] = g; ga[j] = area_fn(g); scol[j] = 0ull;
  }
  if (tid < 64) srow[tid] = 0ull;
  __syncthreads();
  if (tid < 64) {
    const int i = pbase + tid;
    const float* sr = ssc + tid * C_SZ;
    float mx = sr[0]; int mi = 0;
    for (int j = 1; j < C_SZ; ++j) { float v = sr[j]; if (v > mx) { mx = v; mi = j; } }
    float s = 0.0f;
    for (int j = 0; j < C_SZ; ++j) s += expf(sr[j] - mx);
    lse[i] = mx + logf(s);
    // 16B-aligned gather: (84*i + 4*mi) floats is a multiple of 4 floats.
    float4 d = *(const float4*)(deltas + (size_t)i * (4 * C_SZ) + 4 * mi);
    const float* r = sro + tid * 5;
    float4 pb;
    pb.x = r[1] + d.x; pb.y = r[2] + d.y; pb.z = r[3] + d.z; pb.w = r[4] + d.w;
    spred[tid] = pb; sarea[tid] = area_fn(pb);
    pred[i] = pb;
  }
  __syncthreads();
  const int pg = tid & 7;
  const int gg = tid >> 3;
  const int p0 = pg << 3;
  float4 pb[8]; float pa[8]; u32 cl[8]; u64 rk[8];
#pragma unroll
  for (int r = 0; r < 8; ++r) {
    pb[r] = spred[p0 + r];
    pa[r] = sarea[p0 + r];
    cl[r] = 0xFFFFFFFFu - (u32)(pbase + p0 + r);
    rk[r] = 0ull;
  }
  const int jbase = gg << 4;
  const int joff = pg << 1;  // 8 same-gg threads -> distinct j each iter (no atomic collisions)
#pragma unroll 2
  for (int jj = 0; jj < 16; ++jj) {
    const int j = jbase + ((jj + joff) & 15);
    const float4 gb = sg[j];
    const float gba = ga[j];
    const u32 lowj = 0xFFFFFFFFu - (u32)j;
    u64 c = 0ull;
#pragma unroll
    for (int r = 0; r < 8; ++r) {
      float v = iou_rcp(pb[r], gb, pa[r], gba);
      u64 k = ((u64)__float_as_uint(v) << 32) | lowj;
      if (k > rk[r]) rk[r] = k;  // row max; equal-iou tie -> smaller j (larger low32)
      u64 ck = ((u64)__float_as_uint(v) << 32) | cl[r];
      if (ck > c) c = ck;        // col max; equal-iou tie -> smaller pred idx
    }
    atomicMax(&scol[j], c);
  }
#pragma unroll
  for (int r = 0; r < 8; ++r) atomicMax(&srow[p0 + r], rk[r]);
  __syncthreads();
  if (tid < 64) rowkey[pbase + tid] = srow[tid];
  for (int j = tid; j < M_SZ; j += 256) atomicMax(&gkey[j], scol[j]);
}

// ======== kBC: scat + match + pos CE + bucket-store + wave-parallel prefix + compaction
//   + (block 255) selection + spin barrier + neg CE + pair loss + final. 256 blocks (1/CU).
__global__ void __launch_bounds__(256) kBC(const u64* __restrict__ rowkey,
    const u64* __restrict__ gkey, const int* __restrict__ gtc,
    const float* __restrict__ scores, const float* __restrict__ lse,
    const float4* __restrict__ pred, const float4* __restrict__ gtb,
    u32* __restrict__ neg_u, u32* __restrict__ hist0, u64* __restrict__ bins,
    u64* __restrict__ scanst, float4* __restrict__ pp, float4* __restrict__ gp,
    State* st, float* __restrict__ out) {
  __shared__ int sscat[256];   // reused as scan buffer in selection
  __shared__ int swsum[4], sncnt[4];
  __shared__ double sdacc[4];
  __shared__ int s_bpref, s_np, s_nn, s_cp;
  __shared__ int s_d, s_kk, s_cnt;
  __shared__ u32 s_ovf;
  __shared__ u64 sth;
  __shared__ u64 scand[OVF_CAP];
  __shared__ float4 sj[128];
  const int tid = threadIdx.x, b = blockIdx.x;
  const int lane = tid & 63, wid = tid >> 6;
  // ---- phase 1: rebuild scatter table for this block's pred range ----
  sscat[tid] = -1;
  __syncthreads();
  for (int g = tid; g < M_SZ; g += 256) {
    u64 key = gkey[g];
    int pidx = (int)(0xFFFFFFFFu - (u32)key);
    if ((pidx >> 8) == b) atomicMax(&sscat[pidx & 255], g);  // dup idx_g: last (max g) wins
  }
  __syncthreads();
  // ---- phase 2: match (state stays in registers) ----
  const int i = (b << 8) + tid;
  u64 rk = rowkey[i];
  float best = __uint_as_float((u32)(rk >> 32));
  int idxp = (int)(0xFFFFFFFFu - (u32)rk);
  int m;
  if (best < F_LOWER) m = -2;
  else {
    int s = sscat[tid];
    m = (s >= 0) ? s : ((best >= F_UPPER) ? idxp : -1);
  }
  u32 ub = threefry_bits((u32)i, L_SZ >> 1) >> 9;
  const u64 nkey = ((u64)ub << 16) | (u32)i;
  float ce = 0.0f;
  if (m >= 0) {
    ce = lse[i] - scores[(size_t)i * C_SZ + gtc[m]];
  } else if (m == -2) {
    atomicExch(&neg_u[i], ub);  // device-scope store (fallback sweep only)
    u32 bin = ub >> 10;
    u32 pos = atomicAdd(&hist0[bin], 1u);
    if (pos < BIN_CAP) atomicExch(&bins[(size_t)bin * BIN_CAP + pos], nkey);
  }
  u64 balp = __ballot(m >= 0);
  u64 baln = __ballot(m == -2);
  double acc = (double)ce;
  for (int off = 32; off > 0; off >>= 1) acc += __shfl_down(acc, off, 64);
  if (lane == 0) { swsum[wid] = __popcll(balp); sncnt[wid] = __popcll(baln); sdacc[wid] = acc; }
  __syncthreads();
  // ---- phase 3: publish aggregate; wave 0 sums predecessors 64-at-a-time ----
  if (tid == 0) {
    int cp = swsum[0] + swsum[1] + swsum[2] + swsum[3];
    int cn = sncnt[0] + sncnt[1] + sncnt[2] + sncnt[3];
    s_cp = cp;
    atomicAdd(&st->num_pos, cp);
    atomicAdd(&st->num_neg, cn);
    atomicAdd(&st->sum_pos_ce, sdacc[0] + sdacc[1] + sdacc[2] + sdacc[3]);
    __hip_atomic_store(&scanst[b], FLG_AGG | (u64)cp, __ATOMIC_RELEASE, __HIP_MEMORY_SCOPE_AGENT);
  }
  __syncthreads();
  if (wid == 0) {
    u64 runl = 0;
    for (int x = b - 1 - lane; x >= 0; x -= 64) {
      u64 v;
      do { v = ald64(&scanst[x]); } while (v == 0ull);  // all blocks publish AGG promptly
      runl += v & ~FLG_MASK;
    }
    for (int off = 32; off > 0; off >>= 1) runl += __shfl_down(runl, off, 64);
    if (lane == 0) {
      s_bpref = (int)runl;
      if (b == 255) {
        s_np = (int)runl + s_cp;   // total positives (deterministic)
        s_nn = aldi(&st->num_neg); // all publishers' adds visible via acquire loads
      }
    }
  }
  __syncthreads();
  // ---- phase 4: index-ordered compaction ----
  const int bpref = s_bpref;
  if (bpref < MAX_POS) {  // block-uniform
    int flag = (m >= 0) ? 1 : 0;
    int incl = flag;
#pragma unroll
    for (int off = 1; off < 64; off <<= 1) {
      int v = __shfl_up(incl, off, 64);
      if (lane >= off) incl += v;
    }
    if (lane == 63) swsum[wid] = incl;
    __syncthreads();
    int wbase = 0;
    for (int w = 0; w < wid; ++w) wbase += swsum[w];
    int rank = bpref + wbase + incl - flag;
    if (flag && rank < MAX_POS) { pp[rank] = pred[i]; gp[rank] = gtb[m]; }
  }
  // ---- phase 5: negative selection (block 255 only) ----
  if (b == 255) {
    __syncthreads();
    const int np = s_np, nn = s_nn;  // bg_num = round(np * 1.0) = np
    if (np >= nn) {
      if (tid == 0)
        __hip_atomic_store(&st->thresh, ~0ull, __ATOMIC_RELEASE, __HIP_MEMORY_SCOPE_AGENT);
    } else {
      u32 loc[32]; int tsum = 0;
#pragma unroll
      for (int r = 0; r < 32; ++r) { loc[r] = ald32(&hist0[tid * 32 + r]); tsum += (int)loc[r]; }
      sscat[tid] = tsum;
      __syncthreads();
      for (int off = 1; off < 256; off <<= 1) {
        int v = (tid >= off) ? sscat[tid - off] : 0;
        __syncthreads();
        sscat[tid] += v;
        __syncthreads();
      }
      int incl2 = sscat[tid], excl2 = incl2 - tsum;
      if (np >= excl2 && np < incl2) {
        int kk = np - excl2; int d = 0, c = 0;
#pragma unroll
        for (int r = 0; r < 32; ++r) {
          if (kk < (int)loc[r]) { d = tid * 32 + r; c = (int)loc[r]; break; }
          kk -= (int)loc[r];
        }
        s_d = d; s_kk = kk; s_cnt = c;
      }
      if (tid == 0) s_ovf = 0;
      __syncthreads();
      const int d = s_d, kk = s_kk, cnt = s_cnt;
      if (cnt <= BIN_CAP) {
        if (tid < cnt) scand[tid] = ald64(&bins[(size_t)d * BIN_CAP + tid]);
        __syncthreads();
        if (tid < cnt) {
          u64 key = scand[tid];
          int rank = 0;
          for (int u = 0; u < cnt; ++u) rank += (scand[u] < key) ? 1 : 0;
          if (rank == kk) sth = key;  // keys unique -> single writer
        }
      } else {
        // fallback (Poisson(8) > 32: ~1e-12 per bin): sweep neg_u for bin-d keys
        for (int t = tid; t < L_SZ; t += 256) {
          u32 u = ald32(&neg_u[t]);
          if (u != 0xFFFFFFFFu && (int)(u >> 10) == d) {
            u32 pos = atomicAdd(&s_ovf, 1u);
            if (pos < OVF_CAP) scand[pos] = ((u64)u << 16) | (u32)t;
          }
        }
        __syncthreads();
        int c2 = (int)s_ovf; if (c2 > OVF_CAP) c2 = OVF_CAP;
        for (int t = tid; t < c2; t += 256) {
          u64 key = scand[t];
          int rank = 0;
          for (int u = 0; u < c2; ++u) rank += (scand[u] < key) ? 1 : 0;
          if (rank == kk) sth = key;
        }
      }
      __syncthreads();
      if (tid == 0)
        __hip_atomic_store(&st->thresh, sth, __ATOMIC_RELEASE, __HIP_MEMORY_SCOPE_AGENT);
    }
  }
  // ---- phase 6: device spin barrier (all 256 blocks co-resident at 1/CU) ----
  __syncthreads();
  if (tid == 0) {
    __threadfence();
    atomicAdd(&st->barrier, 1u);
    while (ald32(&st->barrier) < 256u) __builtin_amdgcn_s_sleep(2);
  }
  __syncthreads();
  // ---- phase 7: negative CE from registers ----
  const u64 thresh = ald64(&st->thresh);
  double nacc = 0.0;
  if (m == -2 && nkey < thresh)
    nacc = (double)(lse[i] - scores[(size_t)i * C_SZ + (C_SZ - 1)]);  // BACKGROUND=20
  for (int off = 32; off > 0; off >>= 1) nacc += __shfl_down(nacc, off, 64);
  if (lane == 0) sdacc[wid] = nacc;
  __syncthreads();
  if (tid == 0) atomicAdd(&st->sum_neg_ce, sdacc[0] + sdacc[1] + sdacc[2] + sdacc[3]);
  __syncthreads();
  // ---- phase 8: pair smooth-L1 (blocks 0..127 = 8 i-tiles x 16 j-tiles) ----
  if (b < 128) {
    int n = aldi(&st->num_pos); if (n > MAX_POS) n = MAX_POS;
    const int jb = (b & 15) << 7;
    if (tid < 128) {
      int j = jb + tid;
      sj[tid] = (j < n) ? pp[j] : make_float4(0.f, 0.f, 0.f, 0.f);
    }
    __syncthreads();
    const int ii = ((b >> 4) << 8) + tid;
    double pacc = 0.0;
    if (ii < n) {
      float4 g = gp[ii];
      int jend = n - jb; if (jend > 128) jend = 128;
      for (int j = 0; j < jend; ++j) {
        float4 p4 = sj[j];
        pacc += (double)sl1(p4.x - g.x);
        pacc += (double)sl1(p4.y - g.y);
        pacc += (double)sl1(p4.z - g.z);
        pacc += (double)sl1(p4.w - g.w);
      }
    }
    for (int off = 32; off > 0; off >>= 1) pacc += __shfl_down(pacc, off, 64);
    if (lane == 0) sdacc[wid] = pacc;
    __syncthreads();
    if (tid == 0) atomicAdd(&st->bbox_sum, sdacc[0] + sdacc[1] + sdacc[2] + sdacc[3]);
  }
  // ---- phase 9: last block writes final outputs ----
  if (tid == 0) {
    __threadfence();
    u32 dn = atomicAdd(&st->done, 1u);
    if (dn == 255) {  // all contributions at coherent point
      int np = aldi(&st->num_pos), nn = aldi(&st->num_neg);
      double spc = aldd(&st->sum_pos_ce), snc = aldd(&st->sum_neg_ce);
      double bbs = aldd(&st->bbox_sum);
      int nsel = (np < nn) ? np : nn;
      double wsum = (double)(np + nsel);
      out[0] = (float)((spc + snc) / wsum);
      out[1] = (float)bbs;
    }
  }
}

// ---------- launch ----------

extern "C" void kernel_launch(void* const* d_in, const int* in_sizes, int n_in,
                              void* d_out, int out_size, void* d_ws, size_t ws_size,
                              hipStream_t stream) {
  const float* rois   = (const float*)d_in[0];
  const float* scores = (const float*)d_in[1];
  const float* deltas = (const float*)d_in[2];
  const float4* gtb   = (const float4*)d_in[3];
  const int*   gtc    = (const int*)d_in[4];
  float* out = (float*)d_out;

  char* w = (char*)d_ws;
  // zero-init region: State | gkey | hist0 | scanst | neg_u (~300KB memset)
  State* st    = (State*)w;   w += 256;
  u64* gkey    = (u64*)w;     w += (size_t)M_SZ * 8;
  u32* hist0   = (u32*)w;     w += (size_t)NBINS * 4;
  u64* scanst  = (u64*)w;     w += 256 * 8;
  u32* neg_u   = (u32*)w;     w += (size_t)L_SZ * 4;  // 0 != 0xFFFFFFFF sentinel unused; see below
  char* zero_end = w;
  // no-init scratch
  u64* bins    = (u64*)w;     w += (size_t)NBINS * BIN_CAP * 8;
  float4* pred = (float4*)w;  w += (size_t)L_SZ * 16;
  float* lse   = (float*)w;   w += (size_t)L_SZ * 4;
  u64* rowkey  = (u64*)w;     w += (size_t)L_SZ * 8;
  float4* pp   = (float4*)w;  w += (size_t)MAX_POS * 16;
  float4* gp   = (float4*)w;  w += (size_t)MAX_POS * 16;

  // neg_u starts at 0; negatives store ub (>=0). The fallback sweep tests u != 0xFFFFFFFF,
  // so initialize to 0xFF instead of 0 via a second tiny memset.
  hipMemsetAsync(d_ws, 0, (size_t)((char*)neg_u - (char*)d_ws), stream);
  hipMemsetAsync(neg_u, 0xFF, (size_t)L_SZ * 4, stream);

  kA<<<L_SZ / 64, 256, 0, stream>>>(rois, scores, deltas, gtb, pred, lse, rowkey, gkey);
  kBC<<<L_SZ / 256, 256, 0, stream>>>(rowkey, gkey, gtc, scores, lse, pred, gtb,
                                      neg_u, hist0, bins, scanst, pp, gp, st, out);
}

// Round 10
// 175.957 us; speedup vs baseline: 2.4728x; 2.4728x over previous
//
#include <hip/hip_runtime.h>
#include <stdint.h>

typedef unsigned int u32;
typedef unsigned long long u64;

#define F_UPPER 0.4f
#define F_LOWER 0.1f
#define MAX_POS 2048
#define L_SZ 65536
#define M_SZ 512
#define C_SZ 21
#define NBINS 8192
#define BIN_CAP 32
#define OVF_CAP 1024
#define FLG_AGG (1ull << 62)
#define FLG_MASK (3ull << 62)

struct State {
  double sum_pos_ce;
  double sum_neg_ce;
  double bbox_sum;
  int num_pos;
  int num_neg;
  u32 done;
  u32 _pad;
  u64 thresh;
};

__device__ __forceinline__ float area_fn(const float4 a) {
#pragma clang fp contract(off)
  return (a.z - a.x + 1.0f) * (a.w - a.y + 1.0f);
}

// IoU, op order identical to prior rounds (absmax 0 preserved).
__device__ __forceinline__ float iou_rcp(const float4 a, const float4 b, float a1, float a2) {
#pragma clang fp contract(off)
  float iw = fminf(a.z, b.z) - fmaxf(a.x, b.x) + 1.0f;
  iw = fmaxf(iw, 0.0f);
  float ih = fminf(a.w, b.w) - fmaxf(a.y, b.y) + 1.0f;
  ih = fmaxf(ih, 0.0f);
  float inter = iw * ih;
  return inter * __builtin_amdgcn_rcpf(a1 + a2 - inter);
}

__device__ __forceinline__ float sl1(float d) {
#pragma clang fp contract(off)
  float ad = fabsf(d);
  return (ad < 0.01f) ? (50.0f * d * d) : (ad - 0.005f);
}

__device__ __forceinline__ u32 rotl(u32 x, int d) { return (x << d) | (x >> (32 - d)); }

// JAX threefry2x32, key=(0,42); counts = iota(L) split in halves.
__device__ u32 threefry_bits(u32 i, u32 H) {
  u32 x0, x1; bool hi;
  if (i < H) { x0 = i;     x1 = i + H; hi = false; }
  else       { x0 = i - H; x1 = i;     hi = true;  }
  const u32 ks0 = 0u, ks1 = 42u;
  const u32 ks2 = ks0 ^ ks1 ^ 0x1BD11BDAu;
  x0 += ks0; x1 += ks1;
#define RND(r) { x0 += x1; x1 = rotl(x1, r); x1 ^= x0; }
  RND(13) RND(15) RND(26) RND(6)   x0 += ks1; x1 += ks2 + 1u;
  RND(17) RND(29) RND(16) RND(24)  x0 += ks2; x1 += ks0 + 2u;
  RND(13) RND(15) RND(26) RND(6)   x0 += ks0; x1 += ks1 + 3u;
  RND(17) RND(29) RND(16) RND(24)  x0 += ks1; x1 += ks2 + 4u;
  RND(13) RND(15) RND(26) RND(6)   x0 += ks2; x1 += ks0 + 5u;
#undef RND
  return hi ? x1 : x0;
}

// Device-scope atomic loads (cross-XCD visibility, guide §6 G16).
__device__ __forceinline__ u32 ald32(const u32* p) {
  return __hip_atomic_load(p, __ATOMIC_ACQUIRE, __HIP_MEMORY_SCOPE_AGENT);
}
__device__ __forceinline__ u64 ald64(const u64* p) {
  return __hip_atomic_load(p, __ATOMIC_ACQUIRE, __HIP_MEMORY_SCOPE_AGENT);
}
__device__ __forceinline__ int aldi(const int* p) {
  return __hip_atomic_load(p, __ATOMIC_ACQUIRE, __HIP_MEMORY_SCOPE_AGENT);
}
__device__ __forceinline__ double aldd(const double* p) {
  return __hip_atomic_load(p, __ATOMIC_ACQUIRE, __HIP_MEMORY_SCOPE_AGENT);
}

// ======== kA: ROI + single-pass register-microtiled IoU. 1024 blocks, 64 preds/block.
// Micro-tile: pg = tid&7 owns preds 8*pg..+7 (boxes in VGPRs); gg = tid>>3 owns 16 gts.
// Per thread: 16 iters x (1 ds_read_b128 + 1 ds_read_b32 + 8 IoU evals + 1 ds u64 atomic).
__global__ void __launch_bounds__(256) kA(const float* __restrict__ rois,
    const float* __restrict__ scores, const float* __restrict__ deltas,
    const float4* __restrict__ gtb,
    float4* __restrict__ pred, float* __restrict__ lse,
    u64* __restrict__ rowkey, u64* __restrict__ gkey) {
  __shared__ float  ssc[64 * C_SZ];
  __shared__ float  sro[64 * 5];
  __shared__ float4 sg[M_SZ];
  __shared__ float  ga[M_SZ];
  __shared__ u64    scol[M_SZ];
  __shared__ u64    srow[64];
  __shared__ float4 spred[64];
  __shared__ float  sarea[64];
  const int tid = threadIdx.x;
  const int pbase = blockIdx.x << 6;
  for (int k = tid; k < 64 * C_SZ; k += 256) ssc[k] = scores[(size_t)pbase * C_SZ + k];
  for (int k = tid; k < 64 * 5; k += 256)    sro[k] = rois[(size_t)pbase * 5 + k];
  for (int j = tid; j < M_SZ; j += 256) {
    float4 g = gtb[j]; sg[j] = g; ga[j] = area_fn(g); scol[j] = 0ull;
  }
  if (tid < 64) srow[tid] = 0ull;
  __syncthreads();
  if (tid < 64) {
    const int i = pbase + tid;
    const float* sr = ssc + tid * C_SZ;
    float mx = sr[0]; int mi = 0;
    for (int j = 1; j < C_SZ; ++j) { float v = sr[j]; if (v > mx) { mx = v; mi = j; } }
    float s = 0.0f;
    for (int j = 0; j < C_SZ; ++j) s += expf(sr[j] - mx);
    lse[i] = mx + logf(s);
    // 16B-aligned gather: (84*i + 4*mi) floats is a multiple of 4 floats.
    float4 d = *(const float4*)(deltas + (size_t)i * (4 * C_SZ) + 4 * mi);
    const float* r = sro + tid * 5;
    float4 pb;
    pb.x = r[1] + d.x; pb.y = r[2] + d.y; pb.z = r[3] + d.z; pb.w = r[4] + d.w;
    spred[tid] = pb; sarea[tid] = area_fn(pb);
    pred[i] = pb;
  }
  __syncthreads();
  const int pg = tid & 7;
  const int gg = tid >> 3;
  const int p0 = pg << 3;
  float4 pb[8]; float pa[8]; u32 cl[8]; u64 rk[8];
#pragma unroll
  for (int r = 0; r < 8; ++r) {
    pb[r] = spred[p0 + r];
    pa[r] = sarea[p0 + r];
    cl[r] = 0xFFFFFFFFu - (u32)(pbase + p0 + r);
    rk[r] = 0ull;
  }
  const int jbase = gg << 4;
  const int joff = pg << 1;  // 8 same-gg threads -> distinct j each iter (no atomic collisions)
#pragma unroll 2
  for (int jj = 0; jj < 16; ++jj) {
    const int j = jbase + ((jj + joff) & 15);
    const float4 gb = sg[j];
    const float gba = ga[j];
    const u32 lowj = 0xFFFFFFFFu - (u32)j;
    u64 c = 0ull;
#pragma unroll
    for (int r = 0; r < 8; ++r) {
      float v = iou_rcp(pb[r], gb, pa[r], gba);
      u64 k = ((u64)__float_as_uint(v) << 32) | lowj;
      if (k > rk[r]) rk[r] = k;  // row max; equal-iou tie -> smaller j (larger low32)
      u64 ck = ((u64)__float_as_uint(v) << 32) | cl[r];
      if (ck > c) c = ck;        // col max; equal-iou tie -> smaller pred idx
    }
    atomicMax(&scol[j], c);
  }
#pragma unroll
  for (int r = 0; r < 8; ++r) atomicMax(&srow[p0 + r], rk[r]);
  __syncthreads();
  if (tid < 64) rowkey[pbase + tid] = srow[tid];
  for (int j = tid; j < M_SZ; j += 256) atomicMax(&gkey[j], scol[j]);
}

// ======== kB: scat + match + pos CE + bucket-store + wave-parallel prefix + compaction
//             + (block 255) negative selection. 256 blocks (1/CU, all co-resident).
__global__ void __launch_bounds__(256) kB(const u64* __restrict__ rowkey,
    const u64* __restrict__ gkey, const int* __restrict__ gtc,
    const float* __restrict__ scores, const float* __restrict__ lse,
    const float4* __restrict__ pred, const float4* __restrict__ gtb,
    u32* __restrict__ neg_u, u32* __restrict__ hist0, u64* __restrict__ bins,
    u64* __restrict__ scanst, float4* __restrict__ pp, float4* __restrict__ gp,
    State* st) {
  __shared__ int sscat[256];   // reused as scan buffer in selection
  __shared__ int swsum[4], sncnt[4];
  __shared__ double sdacc[4];
  __shared__ int s_bpref, s_np, s_nn, s_cp;
  __shared__ int s_d, s_kk, s_cnt;
  __shared__ u32 s_ovf;
  __shared__ u64 sth;
  __shared__ u64 scand[OVF_CAP];
  const int tid = threadIdx.x, b = blockIdx.x;
  const int lane = tid & 63, wid = tid >> 6;
  // ---- phase 1: rebuild scatter table for this block's pred range ----
  sscat[tid] = -1;
  __syncthreads();
  for (int g = tid; g < M_SZ; g += 256) {
    u64 key = gkey[g];
    int pidx = (int)(0xFFFFFFFFu - (u32)key);
    if ((pidx >> 8) == b) atomicMax(&sscat[pidx & 255], g);  // dup idx_g: last (max g) wins
  }
  __syncthreads();
  // ---- phase 2: match + per-i work ----
  const int i = (b << 8) + tid;
  u64 rk = rowkey[i];
  float best = __uint_as_float((u32)(rk >> 32));
  int idxp = (int)(0xFFFFFFFFu - (u32)rk);
  int m;
  if (best < F_LOWER) m = -2;
  else {
    int s = sscat[tid];
    m = (s >= 0) ? s : ((best >= F_UPPER) ? idxp : -1);
  }
  u32 ub = threefry_bits((u32)i, L_SZ >> 1) >> 9;
  atomicExch(&neg_u[i], (m == -2) ? ub : 0xFFFFFFFFu);  // device-scope store
  float ce = 0.0f;
  if (m >= 0) {
    ce = lse[i] - scores[(size_t)i * C_SZ + gtc[m]];
  } else if (m == -2) {
    u32 bin = ub >> 10;
    u32 pos = atomicAdd(&hist0[bin], 1u);
    if (pos < BIN_CAP) atomicExch(&bins[(size_t)bin * BIN_CAP + pos], ((u64)ub << 16) | (u32)i);
  }
  u64 balp = __ballot(m >= 0);
  u64 baln = __ballot(m == -2);
  double acc = (double)ce;
  for (int off = 32; off > 0; off >>= 1) acc += __shfl_down(acc, off, 64);
  if (lane == 0) { swsum[wid] = __popcll(balp); sncnt[wid] = __popcll(baln); sdacc[wid] = acc; }
  __syncthreads();
  // ---- phase 3: publish aggregate; wave 0 sums predecessors 64-at-a-time ----
  if (tid == 0) {
    int cp = swsum[0] + swsum[1] + swsum[2] + swsum[3];
    int cn = sncnt[0] + sncnt[1] + sncnt[2] + sncnt[3];
    s_cp = cp;
    atomicAdd(&st->num_pos, cp);
    atomicAdd(&st->num_neg, cn);
    atomicAdd(&st->sum_pos_ce, sdacc[0] + sdacc[1] + sdacc[2] + sdacc[3]);
    __hip_atomic_store(&scanst[b], FLG_AGG | (u64)cp, __ATOMIC_RELEASE, __HIP_MEMORY_SCOPE_AGENT);
  }
  __syncthreads();
  if (wid == 0) {
    u64 runl = 0;
    for (int x = b - 1 - lane; x >= 0; x -= 64) {
      u64 v;
      do { v = ald64(&scanst[x]); } while (v == 0ull);  // all blocks publish AGG promptly
      runl += v & ~FLG_MASK;
    }
    for (int off = 32; off > 0; off >>= 1) runl += __shfl_down(runl, off, 64);
    if (lane == 0) {
      s_bpref = (int)runl;
      if (b == 255) {
        s_np = (int)runl + s_cp;   // total positives (deterministic)
        s_nn = aldi(&st->num_neg); // all publishers' adds visible via acquire loads
      }
    }
  }
  __syncthreads();
  // ---- phase 4: index-ordered compaction ----
  const int bpref = s_bpref;
  if (bpref < MAX_POS) {  // block-uniform
    int flag = (m >= 0) ? 1 : 0;
    int incl = flag;
#pragma unroll
    for (int off = 1; off < 64; off <<= 1) {
      int v = __shfl_up(incl, off, 64);
      if (lane >= off) incl += v;
    }
    if (lane == 63) swsum[wid] = incl;
    __syncthreads();
    int wbase = 0;
    for (int w = 0; w < wid; ++w) wbase += swsum[w];
    int rank = bpref + wbase + incl - flag;
    if (flag && rank < MAX_POS) { pp[rank] = pred[i]; gp[rank] = gtb[m]; }
  }
  // ---- phase 5: negative selection (block 255 only) ----
  if (b != 255) return;
  __syncthreads();
  const int np = s_np, nn = s_nn;  // bg_num = round(np * 1.0) = np
  if (np >= nn) {
    if (tid == 0) st->thresh = ~0ull;  // select all negatives
    return;
  }
  u32 loc[32]; int tsum = 0;
#pragma unroll
  for (int r = 0; r < 32; ++r) { loc[r] = ald32(&hist0[tid * 32 + r]); tsum += (int)loc[r]; }
  sscat[tid] = tsum;
  __syncthreads();
  for (int off = 1; off < 256; off <<= 1) {
    int v = (tid >= off) ? sscat[tid - off] : 0;
    __syncthreads();
    sscat[tid] += v;
    __syncthreads();
  }
  int incl2 = sscat[tid], excl2 = incl2 - tsum;
  if (np >= excl2 && np < incl2) {
    int kk = np - excl2; int d = 0, c = 0;
#pragma unroll
    for (int r = 0; r < 32; ++r) {
      if (kk < (int)loc[r]) { d = tid * 32 + r; c = (int)loc[r]; break; }
      kk -= (int)loc[r];
    }
    s_d = d; s_kk = kk; s_cnt = c;
  }
  if (tid == 0) s_ovf = 0;
  __syncthreads();
  const int d = s_d, kk = s_kk, cnt = s_cnt;
  if (cnt <= BIN_CAP) {
    if (tid < cnt) scand[tid] = ald64(&bins[(size_t)d * BIN_CAP + tid]);
    __syncthreads();
    if (tid < cnt) {
      u64 key = scand[tid];
      int rank = 0;
      for (int u = 0; u < cnt; ++u) rank += (scand[u] < key) ? 1 : 0;
      if (rank == kk) sth = key;  // keys unique -> single writer
    }
  } else {
    // fallback (Poisson(8) > 32: ~1e-12 per bin): sweep neg_u for bin-d keys
    for (int t = tid; t < L_SZ; t += 256) {
      u32 u = ald32(&neg_u[t]);
      if (u != 0xFFFFFFFFu && (int)(u >> 10) == d) {
        u32 pos = atomicAdd(&s_ovf, 1u);
        if (pos < OVF_CAP) scand[pos] = ((u64)u << 16) | (u32)t;
      }
    }
    __syncthreads();
    int c2 = (int)s_ovf; if (c2 > OVF_CAP) c2 = OVF_CAP;
    for (int t = tid; t < c2; t += 256) {
      u64 key = scand[t];
      int rank = 0;
      for (int u = 0; u < c2; ++u) rank += (scand[u] < key) ? 1 : 0;
      if (rank == kk) sth = key;
    }
  }
  __syncthreads();
  if (tid == 0) st->thresh = sth;  // select keys strictly below the rank-bg_num key
}

// ======== kC: neg CE (all 256 blocks) + pair smooth-L1 (blocks 0..127) + final write.
__global__ void __launch_bounds__(256) kC(const u32* __restrict__ neg_u,
    const float* __restrict__ scores, const float* __restrict__ lse,
    const float4* __restrict__ pp, const float4* __restrict__ gp,
    State* st, float* __restrict__ out) {
  __shared__ float4 sj[128];
  __shared__ double sdacc[4];
  const int tid = threadIdx.x, b = blockIdx.x;
  const int lane = tid & 63, wid = tid >> 6;
  const u64 thresh = st->thresh;
  const int i = (b << 8) + tid;
  u32 u = neg_u[i];
  double acc = 0.0;
  if (u != 0xFFFFFFFFu) {
    u64 key = ((u64)u << 16) | (u32)i;
    if (key < thresh)
      acc = (double)(lse[i] - scores[(size_t)i * C_SZ + (C_SZ - 1)]);  // BACKGROUND=20
  }
  for (int off = 32; off > 0; off >>= 1) acc += __shfl_down(acc, off, 64);
  if (lane == 0) sdacc[wid] = acc;
  __syncthreads();
  if (tid == 0) atomicAdd(&st->sum_neg_ce, sdacc[0] + sdacc[1] + sdacc[2] + sdacc[3]);
  __syncthreads();
  if (b < 128) {
    int n = st->num_pos; if (n > MAX_POS) n = MAX_POS;
    const int jb = (b & 15) << 7;
    if (tid < 128) {
      int j = jb + tid;
      sj[tid] = (j < n) ? pp[j] : make_float4(0.f, 0.f, 0.f, 0.f);
    }
    __syncthreads();
    const int ii = ((b >> 4) << 8) + tid;
    double pacc = 0.0;
    if (ii < n) {
      float4 g = gp[ii];
      int jend = n - jb; if (jend > 128) jend = 128;
      for (int j = 0; j < jend; ++j) {
        float4 p4 = sj[j];
        pacc += (double)sl1(p4.x - g.x);
        pacc += (double)sl1(p4.y - g.y);
        pacc += (double)sl1(p4.z - g.z);
        pacc += (double)sl1(p4.w - g.w);
      }
    }
    for (int off = 32; off > 0; off >>= 1) pacc += __shfl_down(pacc, off, 64);
    if (lane == 0) sdacc[wid] = pacc;
    __syncthreads();
    if (tid == 0) atomicAdd(&st->bbox_sum, sdacc[0] + sdacc[1] + sdacc[2] + sdacc[3]);
  }
  if (tid == 0) {
    __threadfence();
    u32 dn = atomicAdd(&st->done, 1u);
    if (dn == 255) {  // last block: all contributions at coherent point
      int np = aldi(&st->num_pos), nn = aldi(&st->num_neg);
      double spc = aldd(&st->sum_pos_ce), snc = aldd(&st->sum_neg_ce);
      double bbs = aldd(&st->bbox_sum);
      int nsel = (np < nn) ? np : nn;
      double wsum = (double)(np + nsel);
      out[0] = (float)((spc + snc) / wsum);
      out[1] = (float)bbs;
    }
  }
}

// ---------- launch ----------

extern "C" void kernel_launch(void* const* d_in, const int* in_sizes, int n_in,
                              void* d_out, int out_size, void* d_ws, size_t ws_size,
                              hipStream_t stream) {
  const float* rois   = (const float*)d_in[0];
  const float* scores = (const float*)d_in[1];
  const float* deltas = (const float*)d_in[2];
  const float4* gtb   = (const float4*)d_in[3];
  const int*   gtc    = (const int*)d_in[4];
  float* out = (float*)d_out;

  char* w = (char*)d_ws;
  // zero-init region: State | gkey | hist0 | scanst (~39KB memset)
  State* st    = (State*)w;   w += 256;
  u64* gkey    = (u64*)w;     w += (size_t)M_SZ * 8;
  u32* hist0   = (u32*)w;     w += (size_t)NBINS * 4;
  u64* scanst  = (u64*)w;     w += 256 * 8;
  char* zero_end = w;
  // no-init scratch
  u64* bins    = (u64*)w;     w += (size_t)NBINS * BIN_CAP * 8;
  float4* pred = (float4*)w;  w += (size_t)L_SZ * 16;
  float* lse   = (float*)w;   w += (size_t)L_SZ * 4;
  u64* rowkey  = (u64*)w;     w += (size_t)L_SZ * 8;
  u32* neg_u   = (u32*)w;     w += (size_t)L_SZ * 4;
  float4* pp   = (float4*)w;  w += (size_t)MAX_POS * 16;
  float4* gp   = (float4*)w;  w += (size_t)MAX_POS * 16;

  hipMemsetAsync(d_ws, 0, (size_t)(zero_end - (char*)d_ws), stream);

  kA<<<L_SZ / 64, 256, 0, stream>>>(rois, scores, deltas, gtb, pred, lse, rowkey, gkey);
  kB<<<L_SZ / 256, 256, 0, stream>>>(rowkey, gkey, gtc, scores, lse, pred, gtb,
                                     neg_u, hist0, bins, scanst, pp, gp, st);
  kC<<<L_SZ / 256, 256, 0, stream>>>(neg_u, scores, lse, pp, gp, st, out);
}

// Round 11
// 161.180 us; speedup vs baseline: 2.6995x; 1.0917x over previous
//
#include <hip/hip_runtime.h>
#include <stdint.h>

typedef unsigned int u32;
typedef unsigned long long u64;

#define F_UPPER 0.4f
#define F_LOWER 0.1f
#define MAX_POS 2048
#define L_SZ 65536
#define M_SZ 512
#define C_SZ 21
#define NBINS 8192
#define BIN_CAP 32
#define OVF_CAP 1024
#define FLG_AGG (1ull << 62)
#define FLG_MASK (3ull << 62)

struct State {
  int num_pos;
  int num_neg;
  u64 thresh;
};

__device__ __forceinline__ float area_fn(const float4 a) {
#pragma clang fp contract(off)
  return (a.z - a.x + 1.0f) * (a.w - a.y + 1.0f);
}

// IoU, op order identical to prior rounds (absmax 0 preserved).
__device__ __forceinline__ float iou_rcp(const float4 a, const float4 b, float a1, float a2) {
#pragma clang fp contract(off)
  float iw = fminf(a.z, b.z) - fmaxf(a.x, b.x) + 1.0f;
  iw = fmaxf(iw, 0.0f);
  float ih = fminf(a.w, b.w) - fmaxf(a.y, b.y) + 1.0f;
  ih = fmaxf(ih, 0.0f);
  float inter = iw * ih;
  return inter * __builtin_amdgcn_rcpf(a1 + a2 - inter);
}

__device__ __forceinline__ float sl1(float d) {
#pragma clang fp contract(off)
  float ad = fabsf(d);
  return (ad < 0.01f) ? (50.0f * d * d) : (ad - 0.005f);
}

__device__ __forceinline__ u32 rotl(u32 x, int d) { return (x << d) | (x >> (32 - d)); }

// JAX threefry2x32, key=(0,42); counts = iota(L) split in halves.
__device__ u32 threefry_bits(u32 i, u32 H) {
  u32 x0, x1; bool hi;
  if (i < H) { x0 = i;     x1 = i + H; hi = false; }
  else       { x0 = i - H; x1 = i;     hi = true;  }
  const u32 ks0 = 0u, ks1 = 42u;
  const u32 ks2 = ks0 ^ ks1 ^ 0x1BD11BDAu;
  x0 += ks0; x1 += ks1;
#define RND(r) { x0 += x1; x1 = rotl(x1, r); x1 ^= x0; }
  RND(13) RND(15) RND(26) RND(6)   x0 += ks1; x1 += ks2 + 1u;
  RND(17) RND(29) RND(16) RND(24)  x0 += ks2; x1 += ks0 + 2u;
  RND(13) RND(15) RND(26) RND(6)   x0 += ks0; x1 += ks1 + 3u;
  RND(17) RND(29) RND(16) RND(24)  x0 += ks1; x1 += ks2 + 4u;
  RND(13) RND(15) RND(26) RND(6)   x0 += ks2; x1 += ks0 + 5u;
#undef RND
  return hi ? x1 : x0;
}

// Device-scope atomic loads (cross-XCD visibility, guide §6 G16) — used only where a
// release/acquire pair is required *within* a kernel. Cross-kernel visibility uses the
// kernel boundary (stream order) with plain loads/stores.
__device__ __forceinline__ u32 ald32(const u32* p) {
  return __hip_atomic_load(p, __ATOMIC_ACQUIRE, __HIP_MEMORY_SCOPE_AGENT);
}
__device__ __forceinline__ u64 ald64(const u64* p) {
  return __hip_atomic_load(p, __ATOMIC_ACQUIRE, __HIP_MEMORY_SCOPE_AGENT);
}

// ======== kA: ROI + single-pass register-microtiled IoU. 1024 blocks, 64 preds/block.
// Micro-tile: pg = tid&7 owns preds 8*pg..+7 (boxes in VGPRs); gg = tid>>3 owns 16 gts.
__global__ void __launch_bounds__(256) kA(const float* __restrict__ rois,
    const float* __restrict__ scores, const float* __restrict__ deltas,
    const float4* __restrict__ gtb,
    float4* __restrict__ pred, float* __restrict__ lse,
    u64* __restrict__ rowkey, u64* __restrict__ gkey) {
  __shared__ float  ssc[64 * C_SZ];
  __shared__ float  sro[64 * 5];
  __shared__ float4 sg[M_SZ];
  __shared__ float  ga[M_SZ];
  __shared__ u64    scol[M_SZ];
  __shared__ u64    srow[64];
  __shared__ float4 spred[64];
  __shared__ float  sarea[64];
  const int tid = threadIdx.x;
  const int pbase = blockIdx.x << 6;
  for (int k = tid; k < 64 * C_SZ; k += 256) ssc[k] = scores[(size_t)pbase * C_SZ + k];
  for (int k = tid; k < 64 * 5; k += 256)    sro[k] = rois[(size_t)pbase * 5 + k];
  for (int j = tid; j < M_SZ; j += 256) {
    float4 g = gtb[j]; sg[j] = g; ga[j] = area_fn(g); scol[j] = 0ull;
  }
  if (tid < 64) srow[tid] = 0ull;
  __syncthreads();
  if (tid < 64) {
    const int i = pbase + tid;
    const float* sr = ssc + tid * C_SZ;
    float mx = sr[0]; int mi = 0;
    for (int j = 1; j < C_SZ; ++j) { float v = sr[j]; if (v > mx) { mx = v; mi = j; } }
    float s = 0.0f;
    for (int j = 0; j < C_SZ; ++j) s += expf(sr[j] - mx);
    lse[i] = mx + logf(s);
    // 16B-aligned gather: (84*i + 4*mi) floats is a multiple of 4 floats.
    float4 d = *(const float4*)(deltas + (size_t)i * (4 * C_SZ) + 4 * mi);
    const float* r = sro + tid * 5;
    float4 pb;
    pb.x = r[1] + d.x; pb.y = r[2] + d.y; pb.z = r[3] + d.z; pb.w = r[4] + d.w;
    spred[tid] = pb; sarea[tid] = area_fn(pb);
    pred[i] = pb;
  }
  __syncthreads();
  const int pg = tid & 7;
  const int gg = tid >> 3;
  const int p0 = pg << 3;
  float4 pb[8]; float pa[8]; u32 cl[8]; u64 rk[8];
#pragma unroll
  for (int r = 0; r < 8; ++r) {
    pb[r] = spred[p0 + r];
    pa[r] = sarea[p0 + r];
    cl[r] = 0xFFFFFFFFu - (u32)(pbase + p0 + r);
    rk[r] = 0ull;
  }
  const int jbase = gg << 4;
  const int joff = pg << 1;  // 8 same-gg threads -> distinct j each iter (no atomic collisions)
#pragma unroll 2
  for (int jj = 0; jj < 16; ++jj) {
    const int j = jbase + ((jj + joff) & 15);
    const float4 gb = sg[j];
    const float gba = ga[j];
    const u32 lowj = 0xFFFFFFFFu - (u32)j;
    u64 c = 0ull;
#pragma unroll
    for (int r = 0; r < 8; ++r) {
      float v = iou_rcp(pb[r], gb, pa[r], gba);
      u64 k = ((u64)__float_as_uint(v) << 32) | lowj;
      if (k > rk[r]) rk[r] = k;  // row max; equal-iou tie -> smaller j (larger low32)
      u64 ck = ((u64)__float_as_uint(v) << 32) | cl[r];
      if (ck > c) c = ck;        // col max; equal-iou tie -> smaller pred idx
    }
    atomicMax(&scol[j], c);
  }
#pragma unroll
  for (int r = 0; r < 8; ++r) atomicMax(&srow[p0 + r], rk[r]);
  __syncthreads();
  if (tid < 64) rowkey[pbase + tid] = srow[tid];
  for (int j = tid; j < M_SZ; j += 256) atomicMax(&gkey[j], scol[j]);
}

// ======== kB: scat + match + pos CE partial + bucket-store + packed lookback + compaction
//             + (block 255) negative selection. 256 blocks (1/CU, all co-resident).
// NO hot-path device atomics except hist0 (8192-way spread) and the 1-per-block scanst publish.
__global__ void __launch_bounds__(256) kB(const u64* __restrict__ rowkey,
    const u64* __restrict__ gkey, const int* __restrict__ gtc,
    const float* __restrict__ scores, const float* __restrict__ lse,
    const float4* __restrict__ pred, const float4* __restrict__ gtb,
    u32* __restrict__ neg_u, u32* __restrict__ hist0, u64* __restrict__ bins,
    u64* __restrict__ scanst, double* __restrict__ posce,
    float4* __restrict__ pp, float4* __restrict__ gp, State* st) {
  __shared__ int sscat[256];   // reused as scan buffer in selection
  __shared__ int swsum[4], sncnt[4];
  __shared__ double sdacc[4];
  __shared__ int s_bpref, s_np, s_nn;
  __shared__ int s_d, s_kk, s_cnt;
  __shared__ u32 s_ovf;
  __shared__ u64 sth;
  __shared__ u64 scand[OVF_CAP];
  const int tid = threadIdx.x, b = blockIdx.x;
  const int lane = tid & 63, wid = tid >> 6;
  // ---- phase 1: rebuild scatter table for this block's pred range ----
  sscat[tid] = -1;
  __syncthreads();
  for (int g = tid; g < M_SZ; g += 256) {
    u64 key = gkey[g];
    int pidx = (int)(0xFFFFFFFFu - (u32)key);
    if ((pidx >> 8) == b) atomicMax(&sscat[pidx & 255], g);  // dup idx_g: last (max g) wins
  }
  __syncthreads();
  // ---- phase 2: match + per-i work (plain cached stores; kernel boundary handles kC) ----
  const int i = (b << 8) + tid;
  u64 rk = rowkey[i];
  float best = __uint_as_float((u32)(rk >> 32));
  int idxp = (int)(0xFFFFFFFFu - (u32)rk);
  int m;
  if (best < F_LOWER) m = -2;
  else {
    int s = sscat[tid];
    m = (s >= 0) ? s : ((best >= F_UPPER) ? idxp : -1);
  }
  u32 ub = threefry_bits((u32)i, L_SZ >> 1) >> 9;
  neg_u[i] = (m == -2) ? ub : 0xFFFFFFFFu;  // plain coalesced store
  float ce = 0.0f;
  if (m >= 0) {
    ce = lse[i] - scores[(size_t)i * C_SZ + gtc[m]];
  } else if (m == -2) {
    u32 bin = ub >> 10;
    u32 pos = atomicAdd(&hist0[bin], 1u);    // spread over 8192 bins
    if (pos < BIN_CAP) bins[(size_t)bin * BIN_CAP + pos] = ((u64)ub << 16) | (u32)i;  // plain
  }
  u64 balp = __ballot(m >= 0);
  u64 baln = __ballot(m == -2);
  double acc = (double)ce;
  for (int off = 32; off > 0; off >>= 1) acc += __shfl_down(acc, off, 64);
  if (lane == 0) { swsum[wid] = __popcll(balp); sncnt[wid] = __popcll(baln); sdacc[wid] = acc; }
  __syncthreads();
  // ---- phase 3: publish (cp,cn packed) with release; wave 0 lookback 64-at-a-time ----
  int cp0 = 0, cn0 = 0;
  if (tid == 0) {
    cp0 = swsum[0] + swsum[1] + swsum[2] + swsum[3];
    cn0 = sncnt[0] + sncnt[1] + sncnt[2] + sncnt[3];
    posce[b] = sdacc[0] + sdacc[1] + sdacc[2] + sdacc[3];  // plain; ordered by release below
    __hip_atomic_store(&scanst[b], FLG_AGG | (u64)(u32)(cp0 | (cn0 << 16)),
                       __ATOMIC_RELEASE, __HIP_MEMORY_SCOPE_AGENT);
  }
  __syncthreads();
  if (wid == 0) {
    u64 run2 = 0;  // low32 = sum cp, high32 = sum cn
    for (int x = b - 1 - lane; x >= 0; x -= 64) {
      u64 v;
      do { v = ald64(&scanst[x]); } while (v == 0ull);
      u32 pay = (u32)v;
      run2 += (u64)(pay & 0xFFFFu) | ((u64)(pay >> 16) << 32);
    }
    for (int off = 32; off > 0; off >>= 1) run2 += __shfl_down(run2, off, 64);
    if (lane == 0) {
      s_bpref = (int)(run2 & 0xFFFFFFFFull);
      if (b == 255) {
        s_np = (int)(run2 & 0xFFFFFFFFull) + cp0;  // total positives (deterministic)
        s_nn = (int)(run2 >> 32) + cn0;            // total negatives
      }
    }
  }
  __syncthreads();
  // ---- phase 4: index-ordered compaction ----
  const int bpref = s_bpref;
  if (bpref < MAX_POS) {  // block-uniform
    int flag = (m >= 0) ? 1 : 0;
    int incl = flag;
#pragma unroll
    for (int off = 1; off < 64; off <<= 1) {
      int v = __shfl_up(incl, off, 64);
      if (lane >= off) incl += v;
    }
    if (lane == 63) swsum[wid] = incl;
    __syncthreads();
    int wbase = 0;
    for (int w = 0; w < wid; ++w) wbase += swsum[w];
    int rank = bpref + wbase + incl - flag;
    if (flag && rank < MAX_POS) { pp[rank] = pred[i]; gp[rank] = gtb[m]; }
  }
  // ---- phase 5: negative selection (block 255 only; sole State writer) ----
  if (b != 255) return;
  __syncthreads();
  const int np = s_np, nn = s_nn;  // bg_num = round(np * 1.0) = np
  if (tid == 0) { st->num_pos = np; st->num_neg = nn; }
  if (np >= nn) {
    if (tid == 0) st->thresh = ~0ull;  // select all negatives
    return;
  }
  u32 loc[32]; int tsum = 0;
#pragma unroll
  for (int r = 0; r < 32; ++r) { loc[r] = ald32(&hist0[tid * 32 + r]); tsum += (int)loc[r]; }
  sscat[tid] = tsum;
  __syncthreads();
  for (int off = 1; off < 256; off <<= 1) {
    int v = (tid >= off) ? sscat[tid - off] : 0;
    __syncthreads();
    sscat[tid] += v;
    __syncthreads();
  }
  int incl2 = sscat[tid], excl2 = incl2 - tsum;
  if (np >= excl2 && np < incl2) {
    int kk = np - excl2; int d = 0, c = 0;
#pragma unroll
    for (int r = 0; r < 32; ++r) {
      if (kk < (int)loc[r]) { d = tid * 32 + r; c = (int)loc[r]; break; }
      kk -= (int)loc[r];
    }
    s_d = d; s_kk = kk; s_cnt = c;
  }
  if (tid == 0) s_ovf = 0;
  __syncthreads();
  const int d = s_d, kk = s_kk, cnt = s_cnt;
  if (cnt <= BIN_CAP) {
    if (tid < cnt) scand[tid] = ald64(&bins[(size_t)d * BIN_CAP + tid]);
    __syncthreads();
    if (tid < cnt) {
      u64 key = scand[tid];
      int rank = 0;
      for (int u = 0; u < cnt; ++u) rank += (scand[u] < key) ? 1 : 0;
      if (rank == kk) sth = key;  // keys unique -> single writer
    }
  } else {
    // fallback (Poisson(8) > 32: ~1e-12 per bin): sweep neg_u for bin-d keys
    for (int t = tid; t < L_SZ; t += 256) {
      u32 u = ald32(&neg_u[t]);
      if (u != 0xFFFFFFFFu && (int)(u >> 10) == d) {
        u32 pos = atomicAdd(&s_ovf, 1u);
        if (pos < OVF_CAP) scand[pos] = ((u64)u << 16) | (u32)t;
      }
    }
    __syncthreads();
    int c2 = (int)s_ovf; if (c2 > OVF_CAP) c2 = OVF_CAP;
    for (int t = tid; t < c2; t += 256) {
      u64 key = scand[t];
      int rank = 0;
      for (int u = 0; u < c2; ++u) rank += (scand[u] < key) ? 1 : 0;
      if (rank == kk) sth = key;
    }
  }
  __syncthreads();
  if (tid == 0) st->thresh = sth;  // select keys strictly below the rank-bg_num key
}

// ======== kC: neg CE partials (all 256 blocks) + pair smooth-L1 partials (blocks 0..127).
// All plain loads/stores; no global atomics.
__global__ void __launch_bounds__(256) kC(const u32* __restrict__ neg_u,
    const float* __restrict__ scores, const float* __restrict__ lse,
    const float4* __restrict__ pp, const float4* __restrict__ gp,
    const State* __restrict__ st, double* __restrict__ negce, double* __restrict__ bboxp) {
  __shared__ float4 sj[128];
  __shared__ double sdacc[4];
  const int tid = threadIdx.x, b = blockIdx.x;
  const int lane = tid & 63, wid = tid >> 6;
  const u64 thresh = st->thresh;
  const int i = (b << 8) + tid;
  u32 u = neg_u[i];
  double acc = 0.0;
  if (u != 0xFFFFFFFFu) {
    u64 key = ((u64)u << 16) | (u32)i;
    if (key < thresh)
      acc = (double)(lse[i] - scores[(size_t)i * C_SZ + (C_SZ - 1)]);  // BACKGROUND=20
  }
  for (int off = 32; off > 0; off >>= 1) acc += __shfl_down(acc, off, 64);
  if (lane == 0) sdacc[wid] = acc;
  __syncthreads();
  if (tid == 0) negce[b] = sdacc[0] + sdacc[1] + sdacc[2] + sdacc[3];
  __syncthreads();
  if (b < 128) {
    int n = st->num_pos; if (n > MAX_POS) n = MAX_POS;
    const int jb = (b & 15) << 7;
    if (tid < 128) {
      int j = jb + tid;
      sj[tid] = (j < n) ? pp[j] : make_float4(0.f, 0.f, 0.f, 0.f);
    }
    __syncthreads();
    const int ii = ((b >> 4) << 8) + tid;
    double pacc = 0.0;
    if (ii < n) {
      float4 g = gp[ii];
      int jend = n - jb; if (jend > 128) jend = 128;
      for (int j = 0; j < jend; ++j) {
        float4 p4 = sj[j];
        pacc += (double)sl1(p4.x - g.x);
        pacc += (double)sl1(p4.y - g.y);
        pacc += (double)sl1(p4.z - g.z);
        pacc += (double)sl1(p4.w - g.w);
      }
    }
    for (int off = 32; off > 0; off >>= 1) pacc += __shfl_down(pacc, off, 64);
    if (lane == 0) sdacc[wid] = pacc;
    __syncthreads();
    if (tid == 0) bboxp[b] = sdacc[0] + sdacc[1] + sdacc[2] + sdacc[3];
  }
}

// ======== kD: final reduction of per-block partials. 1 block.
__global__ void __launch_bounds__(256) kD(const double* __restrict__ posce,
    const double* __restrict__ negce, const double* __restrict__ bboxp,
    const State* __restrict__ st, float* __restrict__ out) {
  __shared__ double sce[4], sbb[4];
  const int tid = threadIdx.x;
  const int lane = tid & 63, wid = tid >> 6;
  double a = posce[tid] + negce[tid];
  double bb = (tid < 128) ? bboxp[tid] : 0.0;
  for (int off = 32; off > 0; off >>= 1) {
    a += __shfl_down(a, off, 64);
    bb += __shfl_down(bb, off, 64);
  }
  if (lane == 0) { sce[wid] = a; sbb[wid] = bb; }
  __syncthreads();
  if (tid == 0) {
    double ce = sce[0] + sce[1] + sce[2] + sce[3];
    double bbs = sbb[0] + sbb[1] + sbb[2] + sbb[3];
    int np = st->num_pos, nn = st->num_neg;
    int nsel = (np < nn) ? np : nn;
    double wsum = (double)(np + nsel);
    out[0] = (float)(ce / wsum);
    out[1] = (float)bbs;
  }
}

// ---------- launch ----------

extern "C" void kernel_launch(void* const* d_in, const int* in_sizes, int n_in,
                              void* d_out, int out_size, void* d_ws, size_t ws_size,
                              hipStream_t stream) {
  const float* rois   = (const float*)d_in[0];
  const float* scores = (const float*)d_in[1];
  const float* deltas = (const float*)d_in[2];
  const float4* gtb   = (const float4*)d_in[3];
  const int*   gtc    = (const int*)d_in[4];
  float* out = (float*)d_out;

  char* w = (char*)d_ws;
  // zero-init region: State | gkey | hist0 | scanst (~39KB memset)
  State* st    = (State*)w;   w += 256;
  u64* gkey    = (u64*)w;     w += (size_t)M_SZ * 8;
  u32* hist0   = (u32*)w;     w += (size_t)NBINS * 4;
  u64* scanst  = (u64*)w;     w += 256 * 8;
  char* zero_end = w;
  // no-init scratch (every read slot is written first)
  u64* bins    = (u64*)w;     w += (size_t)NBINS * BIN_CAP * 8;
  float4* pred = (float4*)w;  w += (size_t)L_SZ * 16;
  float* lse   = (float*)w;   w += (size_t)L_SZ * 4;
  u64* rowkey  = (u64*)w;     w += (size_t)L_SZ * 8;
  u32* neg_u   = (u32*)w;     w += (size_t)L_SZ * 4;
  float4* pp   = (float4*)w;  w += (size_t)MAX_POS * 16;
  float4* gp   = (float4*)w;  w += (size_t)MAX_POS * 16;
  double* posce= (double*)w;  w += 256 * 8;
  double* negce= (double*)w;  w += 256 * 8;
  double* bboxp= (double*)w;  w += 128 * 8;

  hipMemsetAsync(d_ws, 0, (size_t)(zero_end - (char*)d_ws), stream);

  kA<<<L_SZ / 64, 256, 0, stream>>>(rois, scores, deltas, gtb, pred, lse, rowkey, gkey);
  kB<<<L_SZ / 256, 256, 0, stream>>>(rowkey, gkey, gtc, scores, lse, pred, gtb,
                                     neg_u, hist0, bins, scanst, posce, pp, gp, st);
  kC<<<L_SZ / 256, 256, 0, stream>>>(neg_u, scores, lse, pp, gp, st, negce, bboxp);
  kD<<<1, 256, 0, stream>>>(posce, negce, bboxp, st, out);
}

// Round 12
// 137.280 us; speedup vs baseline: 3.1694x; 1.1741x over previous
//
#include <hip/hip_runtime.h>
#include <stdint.h>

typedef unsigned int u32;
typedef unsigned long long u64;

#define F_UPPER 0.4f
#define F_LOWER 0.1f
#define MAX_POS 2048
#define L_SZ 65536
#define M_SZ 512
#define C_SZ 21
#define NBINS 8192
#define BIN_CAP 32
#define OVF_CAP 1024

struct State {
  int num_pos;
  int num_neg;
  u64 thresh;
};

__device__ __forceinline__ float area_fn(const float4 a) {
#pragma clang fp contract(off)
  return (a.z - a.x + 1.0f) * (a.w - a.y + 1.0f);
}

// IoU, op order identical to prior rounds (absmax 0 preserved).
__device__ __forceinline__ float iou_rcp(const float4 a, const float4 b, float a1, float a2) {
#pragma clang fp contract(off)
  float iw = fminf(a.z, b.z) - fmaxf(a.x, b.x) + 1.0f;
  iw = fmaxf(iw, 0.0f);
  float ih = fminf(a.w, b.w) - fmaxf(a.y, b.y) + 1.0f;
  ih = fmaxf(ih, 0.0f);
  float inter = iw * ih;
  return inter * __builtin_amdgcn_rcpf(a1 + a2 - inter);
}

__device__ __forceinline__ float sl1(float d) {
#pragma clang fp contract(off)
  float ad = fabsf(d);
  return (ad < 0.01f) ? (50.0f * d * d) : (ad - 0.005f);
}

__device__ __forceinline__ u32 rotl(u32 x, int d) { return (x << d) | (x >> (32 - d)); }

// JAX threefry2x32, key=(0,42); counts = iota(L) split in halves.
__device__ u32 threefry_bits(u32 i, u32 H) {
  u32 x0, x1; bool hi;
  if (i < H) { x0 = i;     x1 = i + H; hi = false; }
  else       { x0 = i - H; x1 = i;     hi = true;  }
  const u32 ks0 = 0u, ks1 = 42u;
  const u32 ks2 = ks0 ^ ks1 ^ 0x1BD11BDAu;
  x0 += ks0; x1 += ks1;
#define RND(r) { x0 += x1; x1 = rotl(x1, r); x1 ^= x0; }
  RND(13) RND(15) RND(26) RND(6)   x0 += ks1; x1 += ks2 + 1u;
  RND(17) RND(29) RND(16) RND(24)  x0 += ks2; x1 += ks0 + 2u;
  RND(13) RND(15) RND(26) RND(6)   x0 += ks0; x1 += ks1 + 3u;
  RND(17) RND(29) RND(16) RND(24)  x0 += ks1; x1 += ks2 + 4u;
  RND(13) RND(15) RND(26) RND(6)   x0 += ks2; x1 += ks0 + 5u;
#undef RND
  return hi ? x1 : x0;
}

// ======== kA: ROI + single-pass register-microtiled IoU. 1024 blocks, 64 preds/block.
// Micro-tile: pg = tid&7 owns preds 8*pg..+7 (boxes in VGPRs); gg = tid>>3 owns 16 gts.
__global__ void __launch_bounds__(256) kA(const float* __restrict__ rois,
    const float* __restrict__ scores, const float* __restrict__ deltas,
    const float4* __restrict__ gtb,
    float4* __restrict__ pred, float* __restrict__ lse,
    u64* __restrict__ rowkey, u64* __restrict__ gkey) {
  __shared__ float  ssc[64 * C_SZ];
  __shared__ float  sro[64 * 5];
  __shared__ float4 sg[M_SZ];
  __shared__ float  ga[M_SZ];
  __shared__ u64    scol[M_SZ];
  __shared__ u64    srow[64];
  __shared__ float4 spred[64];
  __shared__ float  sarea[64];
  const int tid = threadIdx.x;
  const int pbase = blockIdx.x << 6;
  for (int k = tid; k < 64 * C_SZ; k += 256) ssc[k] = scores[(size_t)pbase * C_SZ + k];
  for (int k = tid; k < 64 * 5; k += 256)    sro[k] = rois[(size_t)pbase * 5 + k];
  for (int j = tid; j < M_SZ; j += 256) {
    float4 g = gtb[j]; sg[j] = g; ga[j] = area_fn(g); scol[j] = 0ull;
  }
  if (tid < 64) srow[tid] = 0ull;
  __syncthreads();
  if (tid < 64) {
    const int i = pbase + tid;
    const float* sr = ssc + tid * C_SZ;
    float mx = sr[0]; int mi = 0;
    for (int j = 1; j < C_SZ; ++j) { float v = sr[j]; if (v > mx) { mx = v; mi = j; } }
    float s = 0.0f;
    for (int j = 0; j < C_SZ; ++j) s += expf(sr[j] - mx);
    lse[i] = mx + logf(s);
    // 16B-aligned gather: (84*i + 4*mi) floats is a multiple of 4 floats.
    float4 d = *(const float4*)(deltas + (size_t)i * (4 * C_SZ) + 4 * mi);
    const float* r = sro + tid * 5;
    float4 pb;
    pb.x = r[1] + d.x; pb.y = r[2] + d.y; pb.z = r[3] + d.z; pb.w = r[4] + d.w;
    spred[tid] = pb; sarea[tid] = area_fn(pb);
    pred[i] = pb;
  }
  __syncthreads();
  const int pg = tid & 7;
  const int gg = tid >> 3;
  const int p0 = pg << 3;
  float4 pb[8]; float pa[8]; u32 cl[8]; u64 rk[8];
#pragma unroll
  for (int r = 0; r < 8; ++r) {
    pb[r] = spred[p0 + r];
    pa[r] = sarea[p0 + r];
    cl[r] = 0xFFFFFFFFu - (u32)(pbase + p0 + r);
    rk[r] = 0ull;
  }
  const int jbase = gg << 4;
  const int joff = pg << 1;  // 8 same-gg threads -> distinct j each iter (no atomic collisions)
#pragma unroll 2
  for (int jj = 0; jj < 16; ++jj) {
    const int j = jbase + ((jj + joff) & 15);
    const float4 gb = sg[j];
    const float gba = ga[j];
    const u32 lowj = 0xFFFFFFFFu - (u32)j;
    u64 c = 0ull;
#pragma unroll
    for (int r = 0; r < 8; ++r) {
      float v = iou_rcp(pb[r], gb, pa[r], gba);
      u64 k = ((u64)__float_as_uint(v) << 32) | lowj;
      if (k > rk[r]) rk[r] = k;  // row max; equal-iou tie -> smaller j (larger low32)
      u64 ck = ((u64)__float_as_uint(v) << 32) | cl[r];
      if (ck > c) c = ck;        // col max; equal-iou tie -> smaller pred idx
    }
    atomicMax(&scol[j], c);
  }
#pragma unroll
  for (int r = 0; r < 8; ++r) atomicMax(&srow[p0 + r], rk[r]);
  __syncthreads();
  if (tid < 64) rowkey[pbase + tid] = srow[tid];
  for (int j = tid; j < M_SZ; j += 256) atomicMax(&gkey[j], scol[j]);
}

// ======== kB1: scat + match + pos-CE partial + bucket-store + per-block counts.
// 256 blocks. Zero cross-block communication; visibility via kernel boundary.
__global__ void __launch_bounds__(256) kB1(const u64* __restrict__ rowkey,
    const u64* __restrict__ gkey, const int* __restrict__ gtc,
    const float* __restrict__ scores, const float* __restrict__ lse,
    int* __restrict__ matches, u32* __restrict__ neg_u,
    u32* __restrict__ hist0, u64* __restrict__ bins,
    u32* __restrict__ blockcnt, double* __restrict__ posce) {
  __shared__ int sscat[256];
  __shared__ int swsum[4], sncnt[4];
  __shared__ double sdacc[4];
  const int tid = threadIdx.x, b = blockIdx.x;
  const int lane = tid & 63, wid = tid >> 6;
  // scat rebuild for this block's pred range
  sscat[tid] = -1;
  __syncthreads();
  for (int g = tid; g < M_SZ; g += 256) {
    u64 key = gkey[g];
    int pidx = (int)(0xFFFFFFFFu - (u32)key);
    if ((pidx >> 8) == b) atomicMax(&sscat[pidx & 255], g);  // dup idx_g: last (max g) wins
  }
  __syncthreads();
  const int i = (b << 8) + tid;
  u64 rk = rowkey[i];
  float best = __uint_as_float((u32)(rk >> 32));
  int idxp = (int)(0xFFFFFFFFu - (u32)rk);
  int m;
  if (best < F_LOWER) m = -2;
  else {
    int s = sscat[tid];
    m = (s >= 0) ? s : ((best >= F_UPPER) ? idxp : -1);
  }
  matches[i] = m;                                  // plain coalesced store
  u32 ub = threefry_bits((u32)i, L_SZ >> 1) >> 9;
  neg_u[i] = (m == -2) ? ub : 0xFFFFFFFFu;         // plain coalesced store
  float ce = 0.0f;
  if (m >= 0) {
    ce = lse[i] - scores[(size_t)i * C_SZ + gtc[m]];
  } else if (m == -2) {
    u32 bin = ub >> 10;
    u32 pos = atomicAdd(&hist0[bin], 1u);          // spread over 8192 bins
    if (pos < BIN_CAP) bins[(size_t)bin * BIN_CAP + pos] = ((u64)ub << 16) | (u32)i;
  }
  u64 balp = __ballot(m >= 0);
  u64 baln = __ballot(m == -2);
  double acc = (double)ce;
  for (int off = 32; off > 0; off >>= 1) acc += __shfl_down(acc, off, 64);
  if (lane == 0) { swsum[wid] = __popcll(balp); sncnt[wid] = __popcll(baln); sdacc[wid] = acc; }
  __syncthreads();
  if (tid == 0) {
    u32 cp = (u32)(swsum[0] + swsum[1] + swsum[2] + swsum[3]);
    u32 cn = (u32)(sncnt[0] + sncnt[1] + sncnt[2] + sncnt[3]);
    blockcnt[b] = cp | (cn << 16);
    posce[b] = sdacc[0] + sdacc[1] + sdacc[2] + sdacc[3];
  }
}

// ======== kB2: prefix from blockcnt (boundary-visible) + index-ordered compaction;
// block 255 also runs negative selection with plain loads. 256 blocks.
__global__ void __launch_bounds__(256) kB2(const int* __restrict__ matches,
    const float4* __restrict__ pred, const float4* __restrict__ gtb,
    const u32* __restrict__ blockcnt, float4* __restrict__ pp, float4* __restrict__ gp,
    const u32* __restrict__ hist0, const u64* __restrict__ bins,
    const u32* __restrict__ neg_u, State* st) {
  __shared__ int sscan[256];
  __shared__ int swsum[4], sncnt[4];
  __shared__ int s_d, s_kk, s_cnt;
  __shared__ u32 s_ovf;
  __shared__ u64 sth;
  __shared__ u64 scand[OVF_CAP];
  const int tid = threadIdx.x, b = blockIdx.x;
  const int lane = tid & 63, wid = tid >> 6;
  // local scan of the 256 per-block positive counts
  u32 v = blockcnt[tid];
  int cp = (int)(v & 0xFFFFu), cn = (int)(v >> 16);
  sscan[tid] = cp;
  {  // cn total via wave reduce
    int c = cn;
    for (int off = 32; off > 0; off >>= 1) c += __shfl_down(c, off, 64);
    if (lane == 0) sncnt[wid] = c;
  }
  __syncthreads();
  for (int off = 1; off < 256; off <<= 1) {
    int x = (tid >= off) ? sscan[tid - off] : 0;
    __syncthreads();
    sscan[tid] += x;
    __syncthreads();
  }
  const int bpref = (b == 0) ? 0 : sscan[b - 1];
  const int np = sscan[255];
  const int nn = sncnt[0] + sncnt[1] + sncnt[2] + sncnt[3];
  // compaction
  if (bpref < MAX_POS) {  // block-uniform
    const int i = (b << 8) + tid;
    int m = matches[i];
    int flag = (m >= 0) ? 1 : 0;
    int incl = flag;
#pragma unroll
    for (int off = 1; off < 64; off <<= 1) {
      int x = __shfl_up(incl, off, 64);
      if (lane >= off) incl += x;
    }
    if (lane == 63) swsum[wid] = incl;
    __syncthreads();
    int wbase = 0;
    for (int w = 0; w < wid; ++w) wbase += swsum[w];
    int rank = bpref + wbase + incl - flag;
    if (flag && rank < MAX_POS) { pp[rank] = pred[i]; gp[rank] = gtb[m]; }
  }
  // negative selection (block 255 only; all inputs boundary-visible, plain loads)
  if (b != 255) return;
  __syncthreads();
  if (tid == 0) { st->num_pos = np; st->num_neg = nn; }  // bg_num = round(np*1.0) = np
  if (np >= nn) {
    if (tid == 0) st->thresh = ~0ull;  // select all negatives
    return;
  }
  const uint4* h4 = (const uint4*)hist0;
  u32 loc[32]; int tsum = 0;
#pragma unroll
  for (int r = 0; r < 8; ++r) {
    uint4 hv = h4[tid * 8 + r];
    loc[r*4] = hv.x; loc[r*4+1] = hv.y; loc[r*4+2] = hv.z; loc[r*4+3] = hv.w;
    tsum += (int)(hv.x + hv.y + hv.z + hv.w);
  }
  sscan[tid] = tsum;
  __syncthreads();
  for (int off = 1; off < 256; off <<= 1) {
    int x = (tid >= off) ? sscan[tid - off] : 0;
    __syncthreads();
    sscan[tid] += x;
    __syncthreads();
  }
  int incl2 = sscan[tid], excl2 = incl2 - tsum;
  if (np >= excl2 && np < incl2) {
    int kk = np - excl2; int d = 0, c = 0;
#pragma unroll
    for (int r = 0; r < 32; ++r) {
      if (kk < (int)loc[r]) { d = tid * 32 + r; c = (int)loc[r]; break; }
      kk -= (int)loc[r];
    }
    s_d = d; s_kk = kk; s_cnt = c;
  }
  if (tid == 0) s_ovf = 0;
  __syncthreads();
  const int d = s_d, kk = s_kk, cnt = s_cnt;
  if (cnt <= BIN_CAP) {
    if (tid < cnt) scand[tid] = bins[(size_t)d * BIN_CAP + tid];
    __syncthreads();
    if (tid < cnt) {
      u64 key = scand[tid];
      int rank = 0;
      for (int u = 0; u < cnt; ++u) rank += (scand[u] < key) ? 1 : 0;
      if (rank == kk) sth = key;  // keys unique -> single writer
    }
  } else {
    // fallback (Poisson(8) > 32: ~1e-12 per bin): sweep neg_u for bin-d keys
    for (int t = tid; t < L_SZ; t += 256) {
      u32 u = neg_u[t];
      if (u != 0xFFFFFFFFu && (int)(u >> 10) == d) {
        u32 pos = atomicAdd(&s_ovf, 1u);
        if (pos < OVF_CAP) scand[pos] = ((u64)u << 16) | (u32)t;
      }
    }
    __syncthreads();
    int c2 = (int)s_ovf; if (c2 > OVF_CAP) c2 = OVF_CAP;
    for (int t = tid; t < c2; t += 256) {
      u64 key = scand[t];
      int rank = 0;
      for (int u = 0; u < c2; ++u) rank += (scand[u] < key) ? 1 : 0;
      if (rank == kk) sth = key;
    }
  }
  __syncthreads();
  if (tid == 0) st->thresh = sth;  // select keys strictly below the rank-bg_num key
}

// ======== kC: neg CE partials (all 256 blocks) + pair smooth-L1 partials (blocks 0..127).
// All plain loads/stores; no global atomics.
__global__ void __launch_bounds__(256) kC(const u32* __restrict__ neg_u,
    const float* __restrict__ scores, const float* __restrict__ lse,
    const float4* __restrict__ pp, const float4* __restrict__ gp,
    const State* __restrict__ st, double* __restrict__ negce, double* __restrict__ bboxp) {
  __shared__ float4 sj[128];
  __shared__ double sdacc[4];
  const int tid = threadIdx.x, b = blockIdx.x;
  const int lane = tid & 63, wid = tid >> 6;
  const u64 thresh = st->thresh;
  const int i = (b << 8) + tid;
  u32 u = neg_u[i];
  double acc = 0.0;
  if (u != 0xFFFFFFFFu) {
    u64 key = ((u64)u << 16) | (u32)i;
    if (key < thresh)
      acc = (double)(lse[i] - scores[(size_t)i * C_SZ + (C_SZ - 1)]);  // BACKGROUND=20
  }
  for (int off = 32; off > 0; off >>= 1) acc += __shfl_down(acc, off, 64);
  if (lane == 0) sdacc[wid] = acc;
  __syncthreads();
  if (tid == 0) negce[b] = sdacc[0] + sdacc[1] + sdacc[2] + sdacc[3];
  __syncthreads();
  if (b < 128) {
    int n = st->num_pos; if (n > MAX_POS) n = MAX_POS;
    const int jb = (b & 15) << 7;
    if (tid < 128) {
      int j = jb + tid;
      sj[tid] = (j < n) ? pp[j] : make_float4(0.f, 0.f, 0.f, 0.f);
    }
    __syncthreads();
    const int ii = ((b >> 4) << 8) + tid;
    double pacc = 0.0;
    if (ii < n) {
      float4 g = gp[ii];
      int jend = n - jb; if (jend > 128) jend = 128;
      for (int j = 0; j < jend; ++j) {
        float4 p4 = sj[j];
        pacc += (double)sl1(p4.x - g.x);
        pacc += (double)sl1(p4.y - g.y);
        pacc += (double)sl1(p4.z - g.z);
        pacc += (double)sl1(p4.w - g.w);
      }
    }
    for (int off = 32; off > 0; off >>= 1) pacc += __shfl_down(pacc, off, 64);
    if (lane == 0) sdacc[wid] = pacc;
    __syncthreads();
    if (tid == 0) bboxp[b] = sdacc[0] + sdacc[1] + sdacc[2] + sdacc[3];
  }
}

// ======== kD: final reduction of per-block partials. 1 block.
__global__ void __launch_bounds__(256) kD(const double* __restrict__ posce,
    const double* __restrict__ negce, const double* __restrict__ bboxp,
    const State* __restrict__ st, float* __restrict__ out) {
  __shared__ double sce[4], sbb[4];
  const int tid = threadIdx.x;
  const int lane = tid & 63, wid = tid >> 6;
  double a = posce[tid] + negce[tid];
  double bb = (tid < 128) ? bboxp[tid] : 0.0;
  for (int off = 32; off > 0; off >>= 1) {
    a += __shfl_down(a, off, 64);
    bb += __shfl_down(bb, off, 64);
  }
  if (lane == 0) { sce[wid] = a; sbb[wid] = bb; }
  __syncthreads();
  if (tid == 0) {
    double ce = sce[0] + sce[1] + sce[2] + sce[3];
    double bbs = sbb[0] + sbb[1] + sbb[2] + sbb[3];
    int np = st->num_pos, nn = st->num_neg;
    int nsel = (np < nn) ? np : nn;
    double wsum = (double)(np + nsel);
    out[0] = (float)(ce / wsum);
    out[1] = (float)bbs;
  }
}

// ---------- launch ----------

extern "C" void kernel_launch(void* const* d_in, const int* in_sizes, int n_in,
                              void* d_out, int out_size, void* d_ws, size_t ws_size,
                              hipStream_t stream) {
  const float* rois   = (const float*)d_in[0];
  const float* scores = (const float*)d_in[1];
  const float* deltas = (const float*)d_in[2];
  const float4* gtb   = (const float4*)d_in[3];
  const int*   gtc    = (const int*)d_in[4];
  float* out = (float*)d_out;

  char* w = (char*)d_ws;
  // zero-init region: State | gkey | hist0 (~37KB memset)
  State* st    = (State*)w;   w += 256;
  u64* gkey    = (u64*)w;     w += (size_t)M_SZ * 8;
  u32* hist0   = (u32*)w;     w += (size_t)NBINS * 4;
  char* zero_end = w;
  // no-init scratch (every read slot is written first)
  u64* bins    = (u64*)w;     w += (size_t)NBINS * BIN_CAP * 8;
  float4* pred = (float4*)w;  w += (size_t)L_SZ * 16;
  float* lse   = (float*)w;   w += (size_t)L_SZ * 4;
  u64* rowkey  = (u64*)w;     w += (size_t)L_SZ * 8;
  int* matches = (int*)w;     w += (size_t)L_SZ * 4;
  u32* neg_u   = (u32*)w;     w += (size_t)L_SZ * 4;
  float4* pp   = (float4*)w;  w += (size_t)MAX_POS * 16;
  float4* gp   = (float4*)w;  w += (size_t)MAX_POS * 16;
  u32* blockcnt= (u32*)w;     w += 256 * 4;
  double* posce= (double*)w;  w += 256 * 8;
  double* negce= (double*)w;  w += 256 * 8;
  double* bboxp= (double*)w;  w += 128 * 8;

  hipMemsetAsync(d_ws, 0, (size_t)(zero_end - (char*)d_ws), stream);

  kA<<<L_SZ / 64, 256, 0, stream>>>(rois, scores, deltas, gtb, pred, lse, rowkey, gkey);
  kB1<<<L_SZ / 256, 256, 0, stream>>>(rowkey, gkey, gtc, scores, lse, matches, neg_u,
                                      hist0, bins, blockcnt, posce);
  kB2<<<L_SZ / 256, 256, 0, stream>>>(matches, pred, gtb, blockcnt, pp, gp,
                                      hist0, bins, neg_u, st);
  kC<<<L_SZ / 256, 256, 0, stream>>>(neg_u, scores, lse, pp, gp, st, negce, bboxp);
  kD<<<1, 256, 0, stream>>>(posce, negce, bboxp, st, out);
}

// Round 13
// 136.104 us; speedup vs baseline: 3.1968x; 1.0086x over previous
//
#include <hip/hip_runtime.h>
#include <stdint.h>

typedef unsigned int u32;
typedef unsigned long long u64;

#define F_UPPER 0.4f
#define F_LOWER 0.1f
#define MAX_POS 2048
#define L_SZ 65536
#define M_SZ 512
#define C_SZ 21
#define NBINS 8192
#define BIN_CAP 32
#define OVF_CAP 1024
// High-bit tag so any valid column key beats the harness 0xAA poison pattern under
// unsigned atomicMax (0xAAAA.. < 0xC000..). Valid keys have iou float bits < 0x4000_0000,
// so OR-ing the tag is an order-preserving +constant. Low 32 bits (pred idx) untouched.
#define COL_TAG 0xC000000000000000ull

struct State {
  int num_pos;
  int num_neg;
  u32 done;
  u32 _pad;
  double bbox_sum;
};

__device__ __forceinline__ float area_fn(const float4 a) {
#pragma clang fp contract(off)
  return (a.z - a.x + 1.0f) * (a.w - a.y + 1.0f);
}

// IoU, op order identical to prior rounds (absmax 0 preserved).
__device__ __forceinline__ float iou_rcp(const float4 a, const float4 b, float a1, float a2) {
#pragma clang fp contract(off)
  float iw = fminf(a.z, b.z) - fmaxf(a.x, b.x) + 1.0f;
  iw = fmaxf(iw, 0.0f);
  float ih = fminf(a.w, b.w) - fmaxf(a.y, b.y) + 1.0f;
  ih = fmaxf(ih, 0.0f);
  float inter = iw * ih;
  return inter * __builtin_amdgcn_rcpf(a1 + a2 - inter);
}

__device__ __forceinline__ float sl1(float d) {
#pragma clang fp contract(off)
  float ad = fabsf(d);
  return (ad < 0.01f) ? (50.0f * d * d) : (ad - 0.005f);
}

__device__ __forceinline__ u32 rotl(u32 x, int d) { return (x << d) | (x >> (32 - d)); }

// JAX threefry2x32, key=(0,42); counts = iota(L) split in halves.
__device__ u32 threefry_bits(u32 i, u32 H) {
  u32 x0, x1; bool hi;
  if (i < H) { x0 = i;     x1 = i + H; hi = false; }
  else       { x0 = i - H; x1 = i;     hi = true;  }
  const u32 ks0 = 0u, ks1 = 42u;
  const u32 ks2 = ks0 ^ ks1 ^ 0x1BD11BDAu;
  x0 += ks0; x1 += ks1;
#define RND(r) { x0 += x1; x1 = rotl(x1, r); x1 ^= x0; }
  RND(13) RND(15) RND(26) RND(6)   x0 += ks1; x1 += ks2 + 1u;
  RND(17) RND(29) RND(16) RND(24)  x0 += ks2; x1 += ks0 + 2u;
  RND(13) RND(15) RND(26) RND(6)   x0 += ks0; x1 += ks1 + 3u;
  RND(17) RND(29) RND(16) RND(24)  x0 += ks1; x1 += ks2 + 4u;
  RND(13) RND(15) RND(26) RND(6)   x0 += ks2; x1 += ks0 + 5u;
#undef RND
  return hi ? x1 : x0;
}

// ======== kA: ROI + single-pass register-microtiled IoU + hist0 zeroing.
// 1024 blocks, 64 preds/block. pg=tid&7 owns 8 preds (VGPRs); gg=tid>>3 owns 16 gts.
__global__ void __launch_bounds__(256) kA(const float* __restrict__ rois,
    const float* __restrict__ scores, const float* __restrict__ deltas,
    const float4* __restrict__ gtb,
    float4* __restrict__ pred, float* __restrict__ lse,
    u64* __restrict__ rowkey, u64* __restrict__ gkey, u32* __restrict__ hist0) {
  __shared__ float  ssc[64 * C_SZ];
  __shared__ float  sro[64 * 5];
  __shared__ float4 sg[M_SZ];
  __shared__ float  ga[M_SZ];
  __shared__ u64    scol[M_SZ];
  __shared__ u64    srow[64];
  __shared__ float4 spred[64];
  __shared__ float  sarea[64];
  const int tid = threadIdx.x;
  const int pbase = blockIdx.x << 6;
  if (tid < 8) hist0[(blockIdx.x << 3) + tid] = 0u;  // 1024 blocks x 8 = 8192 entries
  for (int k = tid; k < 64 * C_SZ; k += 256) ssc[k] = scores[(size_t)pbase * C_SZ + k];
  for (int k = tid; k < 64 * 5; k += 256)    sro[k] = rois[(size_t)pbase * 5 + k];
  for (int j = tid; j < M_SZ; j += 256) {
    float4 g = gtb[j]; sg[j] = g; ga[j] = area_fn(g); scol[j] = 0ull;
  }
  if (tid < 64) srow[tid] = 0ull;
  __syncthreads();
  if (tid < 64) {
    const int i = pbase + tid;
    const float* sr = ssc + tid * C_SZ;
    float mx = sr[0]; int mi = 0;
    for (int j = 1; j < C_SZ; ++j) { float v = sr[j]; if (v > mx) { mx = v; mi = j; } }
    float s = 0.0f;
    for (int j = 0; j < C_SZ; ++j) s += expf(sr[j] - mx);
    lse[i] = mx + logf(s);
    // 16B-aligned gather: (84*i + 4*mi) floats is a multiple of 4 floats.
    float4 d = *(const float4*)(deltas + (size_t)i * (4 * C_SZ) + 4 * mi);
    const float* r = sro + tid * 5;
    float4 pb;
    pb.x = r[1] + d.x; pb.y = r[2] + d.y; pb.z = r[3] + d.z; pb.w = r[4] + d.w;
    spred[tid] = pb; sarea[tid] = area_fn(pb);
    pred[i] = pb;
  }
  __syncthreads();
  const int pg = tid & 7;
  const int gg = tid >> 3;
  const int p0 = pg << 3;
  float4 pb[8]; float pa[8]; u32 cl[8]; u64 rk[8];
#pragma unroll
  for (int r = 0; r < 8; ++r) {
    pb[r] = spred[p0 + r];
    pa[r] = sarea[p0 + r];
    cl[r] = 0xFFFFFFFFu - (u32)(pbase + p0 + r);
    rk[r] = 0ull;
  }
  const int jbase = gg << 4;
  const int joff = pg << 1;  // 8 same-gg threads -> distinct j each iter (no atomic collisions)
#pragma unroll 2
  for (int jj = 0; jj < 16; ++jj) {
    const int j = jbase + ((jj + joff) & 15);
    const float4 gb = sg[j];
    const float gba = ga[j];
    const u32 lowj = 0xFFFFFFFFu - (u32)j;
    u64 c = 0ull;
#pragma unroll
    for (int r = 0; r < 8; ++r) {
      float v = iou_rcp(pb[r], gb, pa[r], gba);
      u64 k = ((u64)__float_as_uint(v) << 32) | lowj;
      if (k > rk[r]) rk[r] = k;  // row max; equal-iou tie -> smaller j (larger low32)
      u64 ck = ((u64)__float_as_uint(v) << 32) | cl[r];
      if (ck > c) c = ck;        // col max; equal-iou tie -> smaller pred idx
    }
    atomicMax(&scol[j], c);
  }
#pragma unroll
  for (int r = 0; r < 8; ++r) atomicMax(&srow[p0 + r], rk[r]);
  __syncthreads();
  if (tid < 64) rowkey[pbase + tid] = srow[tid];
  for (int j = tid; j < M_SZ; j += 256) atomicMax(&gkey[j], scol[j] | COL_TAG);
}

// ======== kB1: scat + match + pos-CE partial + bucket-store + per-block counts.
// 256 blocks. Zero cross-block communication; visibility via kernel boundary.
__global__ void __launch_bounds__(256) kB1(const u64* __restrict__ rowkey,
    const u64* __restrict__ gkey, const int* __restrict__ gtc,
    const float* __restrict__ scores, const float* __restrict__ lse,
    int* __restrict__ matches, u32* __restrict__ neg_u,
    u32* __restrict__ hist0, u64* __restrict__ bins,
    u32* __restrict__ blockcnt, double* __restrict__ posce) {
  __shared__ int sscat[256];
  __shared__ int swsum[4], sncnt[4];
  __shared__ double sdacc[4];
  const int tid = threadIdx.x, b = blockIdx.x;
  const int lane = tid & 63, wid = tid >> 6;
  sscat[tid] = -1;
  __syncthreads();
  for (int g = tid; g < M_SZ; g += 256) {
    u64 key = gkey[g];
    int pidx = (int)(0xFFFFFFFFu - (u32)key);  // low32 decode unaffected by COL_TAG
    if ((pidx >> 8) == b) atomicMax(&sscat[pidx & 255], g);  // dup idx_g: last (max g) wins
  }
  __syncthreads();
  const int i = (b << 8) + tid;
  u64 rk = rowkey[i];
  float best = __uint_as_float((u32)(rk >> 32));
  int idxp = (int)(0xFFFFFFFFu - (u32)rk);
  int m;
  if (best < F_LOWER) m = -2;
  else {
    int s = sscat[tid];
    m = (s >= 0) ? s : ((best >= F_UPPER) ? idxp : -1);
  }
  matches[i] = m;
  u32 ub = threefry_bits((u32)i, L_SZ >> 1) >> 9;
  neg_u[i] = (m == -2) ? ub : 0xFFFFFFFFu;
  float ce = 0.0f;
  if (m >= 0) {
    ce = lse[i] - scores[(size_t)i * C_SZ + gtc[m]];
  } else if (m == -2) {
    u32 bin = ub >> 10;
    u32 pos = atomicAdd(&hist0[bin], 1u);          // spread over 8192 bins
    if (pos < BIN_CAP) bins[(size_t)bin * BIN_CAP + pos] = ((u64)ub << 16) | (u32)i;
  }
  u64 balp = __ballot(m >= 0);
  u64 baln = __ballot(m == -2);
  double acc = (double)ce;
  for (int off = 32; off > 0; off >>= 1) acc += __shfl_down(acc, off, 64);
  if (lane == 0) { swsum[wid] = __popcll(balp); sncnt[wid] = __popcll(baln); sdacc[wid] = acc; }
  __syncthreads();
  if (tid == 0) {
    u32 cp = (u32)(swsum[0] + swsum[1] + swsum[2] + swsum[3]);
    u32 cn = (u32)(sncnt[0] + sncnt[1] + sncnt[2] + sncnt[3]);
    blockcnt[b] = cp | (cn << 16);
    posce[b] = sdacc[0] + sdacc[1] + sdacc[2] + sdacc[3];
  }
}

// ======== kB2: blockcnt scan + compaction + REDUNDANT per-block selection + neg-CE
// partials; block 255 initializes State. 256 blocks. All inputs boundary-visible.
__global__ void __launch_bounds__(256) kB2(const int* __restrict__ matches,
    const float4* __restrict__ pred, const float4* __restrict__ gtb,
    const u32* __restrict__ blockcnt, float4* __restrict__ pp, float4* __restrict__ gp,
    const u32* __restrict__ hist0, const u64* __restrict__ bins,
    const u32* __restrict__ neg_u, const float* __restrict__ scores,
    const float* __restrict__ lse, double* __restrict__ negce, State* st) {
  __shared__ int sscan[256];
  __shared__ int swsum[4], sncnt[4];
  __shared__ double sdacc[4];
  __shared__ int s_d, s_kk, s_cnt;
  __shared__ u32 s_ovf;
  __shared__ u64 sth;
  __shared__ u64 scand[OVF_CAP];
  const int tid = threadIdx.x, b = blockIdx.x;
  const int lane = tid & 63, wid = tid >> 6;
  // local scan of per-block counts
  u32 v = blockcnt[tid];
  int cp = (int)(v & 0xFFFFu), cn = (int)(v >> 16);
  sscan[tid] = cp;
  {
    int c = cn;
    for (int off = 32; off > 0; off >>= 1) c += __shfl_down(c, off, 64);
    if (lane == 0) sncnt[wid] = c;
  }
  __syncthreads();
  for (int off = 1; off < 256; off <<= 1) {
    int x = (tid >= off) ? sscan[tid - off] : 0;
    __syncthreads();
    sscan[tid] += x;
    __syncthreads();
  }
  const int bpref = (b == 0) ? 0 : sscan[b - 1];
  const int np = sscan[255];
  const int nn = sncnt[0] + sncnt[1] + sncnt[2] + sncnt[3];
  const int i = (b << 8) + tid;
  const int m = matches[i];
  // compaction
  if (bpref < MAX_POS) {  // block-uniform
    int flag = (m >= 0) ? 1 : 0;
    int incl = flag;
#pragma unroll
    for (int off = 1; off < 64; off <<= 1) {
      int x = __shfl_up(incl, off, 64);
      if (lane >= off) incl += x;
    }
    if (lane == 63) swsum[wid] = incl;
    __syncthreads();
    int wbase = 0;
    for (int w = 0; w < wid; ++w) wbase += swsum[w];
    int rank = bpref + wbase + incl - flag;
    if (flag && rank < MAX_POS) { pp[rank] = pred[i]; gp[rank] = gtb[m]; }
  }
  __syncthreads();
  // redundant negative selection (every block; ~32KB L2-hot hist + <=32-cand rank select)
  u64 thresh = ~0ull;  // np >= nn -> all negatives selected (bg_num = round(np*1.0) = np)
  if (np < nn) {
    const uint4* h4 = (const uint4*)hist0;
    u32 loc[32]; int tsum = 0;
#pragma unroll
    for (int r = 0; r < 8; ++r) {
      uint4 hv = h4[tid * 8 + r];
      loc[r*4] = hv.x; loc[r*4+1] = hv.y; loc[r*4+2] = hv.z; loc[r*4+3] = hv.w;
      tsum += (int)(hv.x + hv.y + hv.z + hv.w);
    }
    sscan[tid] = tsum;
    __syncthreads();
    for (int off = 1; off < 256; off <<= 1) {
      int x = (tid >= off) ? sscan[tid - off] : 0;
      __syncthreads();
      sscan[tid] += x;
      __syncthreads();
    }
    int incl2 = sscan[tid], excl2 = incl2 - tsum;
    if (np >= excl2 && np < incl2) {
      int kk = np - excl2; int d = 0, c = 0;
#pragma unroll
      for (int r = 0; r < 32; ++r) {
        if (kk < (int)loc[r]) { d = tid * 32 + r; c = (int)loc[r]; break; }
        kk -= (int)loc[r];
      }
      s_d = d; s_kk = kk; s_cnt = c;
    }
    if (tid == 0) s_ovf = 0;
    __syncthreads();
    const int d = s_d, kk = s_kk, cnt = s_cnt;
    if (cnt <= BIN_CAP) {
      if (tid < cnt) scand[tid] = bins[(size_t)d * BIN_CAP + tid];
      __syncthreads();
      if (tid < cnt) {
        u64 key = scand[tid];
        int rank = 0;
        for (int u = 0; u < cnt; ++u) rank += (scand[u] < key) ? 1 : 0;
        if (rank == kk) sth = key;  // keys unique -> single writer
      }
    } else {
      // fallback (Poisson(8) > 32: ~1e-12 per bin): sweep neg_u for bin-d keys
      for (int t = tid; t < L_SZ; t += 256) {
        u32 u = neg_u[t];
        if (u != 0xFFFFFFFFu && (int)(u >> 10) == d) {
          u32 pos = atomicAdd(&s_ovf, 1u);
          if (pos < OVF_CAP) scand[pos] = ((u64)u << 16) | (u32)t;
        }
      }
      __syncthreads();
      int c2 = (int)s_ovf; if (c2 > OVF_CAP) c2 = OVF_CAP;
      for (int t = tid; t < c2; t += 256) {
        u64 key = scand[t];
        int rank = 0;
        for (int u = 0; u < c2; ++u) rank += (scand[u] < key) ? 1 : 0;
        if (rank == kk) sth = key;
      }
    }
    __syncthreads();
    thresh = sth;  // select keys strictly below the rank-bg_num key
  }
  // negative CE partial for own range
  double acc = 0.0;
  if (m == -2) {
    u32 u = neg_u[i];
    u64 key = ((u64)u << 16) | (u32)i;
    if (key < thresh)
      acc = (double)(lse[i] - scores[(size_t)i * C_SZ + (C_SZ - 1)]);  // BACKGROUND=20
  }
  for (int off = 32; off > 0; off >>= 1) acc += __shfl_down(acc, off, 64);
  if (lane == 0) sdacc[wid] = acc;
  __syncthreads();
  if (tid == 0) {
    negce[b] = sdacc[0] + sdacc[1] + sdacc[2] + sdacc[3];
    if (b == 255) {  // initialize State for kC (0xAA-poisoned otherwise)
      st->num_pos = np; st->num_neg = nn;
      st->done = 0; st->bbox_sum = 0.0;
    }
  }
}

// ======== kC: pair smooth-L1 (128 blocks = 8 i-tiles x 16 j-tiles) + last-block final.
__global__ void __launch_bounds__(256) kC(const float4* __restrict__ pp,
    const float4* __restrict__ gp, const double* __restrict__ posce,
    const double* __restrict__ negce, State* st, float* __restrict__ out) {
  __shared__ float4 sj[128];
  __shared__ double sdacc[4];
  __shared__ int s_last;
  const int tid = threadIdx.x, b = blockIdx.x;
  const int lane = tid & 63, wid = tid >> 6;
  int n = st->num_pos; if (n > MAX_POS) n = MAX_POS;
  const int jb = (b & 15) << 7;
  if (tid < 128) {
    int j = jb + tid;
    sj[tid] = (j < n) ? pp[j] : make_float4(0.f, 0.f, 0.f, 0.f);
  }
  __syncthreads();
  const int ii = ((b >> 4) << 8) + tid;
  double pacc = 0.0;
  if (ii < n) {
    float4 g = gp[ii];
    int jend = n - jb; if (jend > 128) jend = 128;
    for (int j = 0; j < jend; ++j) {
      float4 p4 = sj[j];
      pacc += (double)sl1(p4.x - g.x);
      pacc += (double)sl1(p4.y - g.y);
      pacc += (double)sl1(p4.z - g.z);
      pacc += (double)sl1(p4.w - g.w);
    }
  }
  for (int off = 32; off > 0; off >>= 1) pacc += __shfl_down(pacc, off, 64);
  if (lane == 0) sdacc[wid] = pacc;
  __syncthreads();
  if (tid == 0) {
    atomicAdd(&st->bbox_sum, sdacc[0] + sdacc[1] + sdacc[2] + sdacc[3]);
    __threadfence();
    u32 dn = atomicAdd(&st->done, 1u);
    s_last = (dn == 127) ? 1 : 0;
  }
  __syncthreads();
  if (!s_last) return;
  // last block: all bbox adds happened-before (fence + done order); reduce CE partials
  double a = posce[tid] + negce[tid];
  for (int off = 32; off > 0; off >>= 1) a += __shfl_down(a, off, 64);
  if (lane == 0) sdacc[wid] = a;
  __syncthreads();
  if (tid == 0) {
    double ce = sdacc[0] + sdacc[1] + sdacc[2] + sdacc[3];
    double bbs = __hip_atomic_load(&st->bbox_sum, __ATOMIC_ACQUIRE, __HIP_MEMORY_SCOPE_AGENT);
    int np = st->num_pos, nn = st->num_neg;
    int nsel = (np < nn) ? np : nn;
    double wsum = (double)(np + nsel);
    out[0] = (float)(ce / wsum);
    out[1] = (float)bbs;
  }
}

// ---------- launch ----------

extern "C" void kernel_launch(void* const* d_in, const int* in_sizes, int n_in,
                              void* d_out, int out_size, void* d_ws, size_t ws_size,
                              hipStream_t stream) {
  const float* rois   = (const float*)d_in[0];
  const float* scores = (const float*)d_in[1];
  const float* deltas = (const float*)d_in[2];
  const float4* gtb   = (const float4*)d_in[3];
  const int*   gtc    = (const int*)d_in[4];
  float* out = (float*)d_out;

  char* w = (char*)d_ws;
  // NO memset: gkey uses COL_TAG so poison always loses under atomicMax (idempotent on
  // stale reruns); hist0 zeroed inside kA; everything else is written before read.
  State* st    = (State*)w;   w += 256;
  u64* gkey    = (u64*)w;     w += (size_t)M_SZ * 8;
  u32* hist0   = (u32*)w;     w += (size_t)NBINS * 4;
  u64* bins    = (u64*)w;     w += (size_t)NBINS * BIN_CAP * 8;
  float4* pred = (float4*)w;  w += (size_t)L_SZ * 16;
  float* lse   = (float*)w;   w += (size_t)L_SZ * 4;
  u64* rowkey  = (u64*)w;     w += (size_t)L_SZ * 8;
  int* matches = (int*)w;     w += (size_t)L_SZ * 4;
  u32* neg_u   = (u32*)w;     w += (size_t)L_SZ * 4;
  float4* pp   = (float4*)w;  w += (size_t)MAX_POS * 16;
  float4* gp   = (float4*)w;  w += (size_t)MAX_POS * 16;
  u32* blockcnt= (u32*)w;     w += 256 * 4;
  double* posce= (double*)w;  w += 256 * 8;
  double* negce= (double*)w;  w += 256 * 8;

  kA<<<L_SZ / 64, 256, 0, stream>>>(rois, scores, deltas, gtb, pred, lse, rowkey, gkey, hist0);
  kB1<<<L_SZ / 256, 256, 0, stream>>>(rowkey, gkey, gtc, scores, lse, matches, neg_u,
                                      hist0, bins, blockcnt, posce);
  kB2<<<L_SZ / 256, 256, 0, stream>>>(matches, pred, gtb, blockcnt, pp, gp,
                                      hist0, bins, neg_u, scores, lse, negce, st);
  kC<<<128, 256, 0, stream>>>(pp, gp, posce, negce, st, out);
}

// Round 14
// 133.058 us; speedup vs baseline: 3.2700x; 1.0229x over previous
//
#include <hip/hip_runtime.h>
#include <stdint.h>

typedef unsigned int u32;
typedef unsigned long long u64;

#define F_UPPER 0.4f
#define F_LOWER 0.1f
#define MAX_POS 2048
#define L_SZ 65536
#define M_SZ 512
#define C_SZ 21
#define NBINS 8192
#define BIN_CAP 32
#define OVF_CAP 1024
// High-bit tag so any valid column key beats the harness 0xAA poison pattern under
// unsigned atomicMax (0xAAAA.. < 0xC000..). Valid keys have iou float bits < 0x4000_0000,
// so OR-ing the tag is an order-preserving +constant. Low 32 bits (pred idx) untouched.
#define COL_TAG 0xC000000000000000ull

struct State {
  int num_pos;
  int num_neg;
  u32 done;
  u32 _pad;
  double bbox_sum;
};

__device__ __forceinline__ float area_fn(const float4 a) {
#pragma clang fp contract(off)
  return (a.z - a.x + 1.0f) * (a.w - a.y + 1.0f);
}

// IoU, op order identical to prior rounds (absmax 0 preserved).
__device__ __forceinline__ float iou_rcp(const float4 a, const float4 b, float a1, float a2) {
#pragma clang fp contract(off)
  float iw = fminf(a.z, b.z) - fmaxf(a.x, b.x) + 1.0f;
  iw = fmaxf(iw, 0.0f);
  float ih = fminf(a.w, b.w) - fmaxf(a.y, b.y) + 1.0f;
  ih = fmaxf(ih, 0.0f);
  float inter = iw * ih;
  return inter * __builtin_amdgcn_rcpf(a1 + a2 - inter);
}

__device__ __forceinline__ float sl1(float d) {
#pragma clang fp contract(off)
  float ad = fabsf(d);
  return (ad < 0.01f) ? (50.0f * d * d) : (ad - 0.005f);
}

__device__ __forceinline__ u32 rotl(u32 x, int d) { return (x << d) | (x >> (32 - d)); }

// JAX threefry2x32, key=(0,42); counts = iota(L) split in halves.
__device__ u32 threefry_bits(u32 i, u32 H) {
  u32 x0, x1; bool hi;
  if (i < H) { x0 = i;     x1 = i + H; hi = false; }
  else       { x0 = i - H; x1 = i;     hi = true;  }
  const u32 ks0 = 0u, ks1 = 42u;
  const u32 ks2 = ks0 ^ ks1 ^ 0x1BD11BDAu;
  x0 += ks0; x1 += ks1;
#define RND(r) { x0 += x1; x1 = rotl(x1, r); x1 ^= x0; }
  RND(13) RND(15) RND(26) RND(6)   x0 += ks1; x1 += ks2 + 1u;
  RND(17) RND(29) RND(16) RND(24)  x0 += ks2; x1 += ks0 + 2u;
  RND(13) RND(15) RND(26) RND(6)   x0 += ks0; x1 += ks1 + 3u;
  RND(17) RND(29) RND(16) RND(24)  x0 += ks1; x1 += ks2 + 4u;
  RND(13) RND(15) RND(26) RND(6)   x0 += ks2; x1 += ks0 + 5u;
#undef RND
  return hi ? x1 : x0;
}

// ======== kA: ROI + single-pass register-microtiled IoU + hist0 zeroing.
// 1024 blocks, 64 preds/block. pg=tid&7 owns 8 preds (VGPRs); gg=tid>>3 owns 16 gts.
// Float-compare argmax tracking; col merge skips IoU==0 (kills same-address atomic chains).
__global__ void __launch_bounds__(256) kA(const float* __restrict__ rois,
    const float* __restrict__ scores, const float* __restrict__ deltas,
    const float4* __restrict__ gtb,
    float4* __restrict__ pred, float* __restrict__ lse,
    u64* __restrict__ rowkey, u64* __restrict__ gkey, u32* __restrict__ hist0) {
  __shared__ float  ssc[64 * C_SZ];
  __shared__ float  sro[64 * 5];
  __shared__ float4 sg[M_SZ];
  __shared__ float  ga[M_SZ];
  __shared__ u64    scol[M_SZ];
  __shared__ u64    srow[64];
  __shared__ float4 spred[64];
  __shared__ float  sarea[64];
  const int tid = threadIdx.x;
  const int pbase = blockIdx.x << 6;
  if (tid < 8) hist0[(blockIdx.x << 3) + tid] = 0u;  // 1024 blocks x 8 = 8192 entries
  for (int k = tid; k < 64 * C_SZ; k += 256) ssc[k] = scores[(size_t)pbase * C_SZ + k];
  for (int k = tid; k < 64 * 5; k += 256)    sro[k] = rois[(size_t)pbase * 5 + k];
  for (int j = tid; j < M_SZ; j += 256) {
    float4 g = gtb[j]; sg[j] = g; ga[j] = area_fn(g); scol[j] = 0ull;
  }
  if (tid < 64) srow[tid] = 0ull;
  __syncthreads();
  if (tid < 64) {
    const int i = pbase + tid;
    const float* sr = ssc + tid * C_SZ;
    float mx = sr[0]; int mi = 0;
    for (int j = 1; j < C_SZ; ++j) { float v = sr[j]; if (v > mx) { mx = v; mi = j; } }
    float s = 0.0f;
    for (int j = 0; j < C_SZ; ++j) s += expf(sr[j] - mx);
    lse[i] = mx + logf(s);
    // 16B-aligned gather: (84*i + 4*mi) floats is a multiple of 4 floats.
    float4 d = *(const float4*)(deltas + (size_t)i * (4 * C_SZ) + 4 * mi);
    const float* r = sro + tid * 5;
    float4 pb;
    pb.x = r[1] + d.x; pb.y = r[2] + d.y; pb.z = r[3] + d.z; pb.w = r[4] + d.w;
    spred[tid] = pb; sarea[tid] = area_fn(pb);
    pred[i] = pb;
  }
  __syncthreads();
  const int pg = tid & 7;
  const int gg = tid >> 3;
  const int p0 = pg << 3;
  float4 pb[8]; float pa[8]; float rbest[8]; int rbj[8];
#pragma unroll
  for (int r = 0; r < 8; ++r) {
    pb[r] = spred[p0 + r];
    pa[r] = sarea[p0 + r];
    rbest[r] = -1.0f;  // first eval (v>=0) always replaces
    rbj[r] = 0;
  }
  const int jbase = gg << 4;
  const int joff = pg << 1;  // 8 same-gg threads -> distinct j each iter (no atomic collisions)
#pragma unroll 2
  for (int jj = 0; jj < 16; ++jj) {
    const int j = jbase + ((jj + joff) & 15);
    const float4 gb = sg[j];
    const float gba = ga[j];
    float cbest = 0.0f; int cbp = 0;
#pragma unroll
    for (int r = 0; r < 8; ++r) {
      float v = iou_rcp(pb[r], gb, pa[r], gba);
      if (v > rbest[r]) { rbest[r] = v; rbj[r] = j; }  // row max (ties measure-zero, see note)
      if (v > cbest) { cbest = v; cbp = r; }           // col max among owned preds
    }
    if (cbest > 0.0f) {  // zero-IoU columns can't define a consumed argmax; skip merge
      u64 c = ((u64)__float_as_uint(cbest) << 32) |
              (u32)(0xFFFFFFFFu - (u32)(pbase + p0 + cbp));
      atomicMax(&scol[j], c);
    }
  }
#pragma unroll
  for (int r = 0; r < 8; ++r) {
    u64 k = ((u64)__float_as_uint(rbest[r]) << 32) | (u32)(0xFFFFFFFFu - (u32)rbj[r]);
    atomicMax(&srow[p0 + r], k);
  }
  __syncthreads();
  if (tid < 64) rowkey[pbase + tid] = srow[tid];
  // Global col merge: only blocks with a positive-IoU local max write (few per gt).
  for (int j = tid; j < M_SZ; j += 256) {
    u64 c = scol[j];
    if ((c >> 32) != 0ull) atomicMax(&gkey[j], c | COL_TAG);
  }
}

// ======== kB1: scat + match + pos-CE partial + bucket-store + per-block counts.
// 256 blocks. Zero cross-block communication; visibility via kernel boundary.
__global__ void __launch_bounds__(256) kB1(const u64* __restrict__ rowkey,
    const u64* __restrict__ gkey, const int* __restrict__ gtc,
    const float* __restrict__ scores, const float* __restrict__ lse,
    int* __restrict__ matches, u32* __restrict__ neg_u,
    u32* __restrict__ hist0, u64* __restrict__ bins,
    u32* __restrict__ blockcnt, double* __restrict__ posce) {
  __shared__ int sscat[256];
  __shared__ int swsum[4], sncnt[4];
  __shared__ double sdacc[4];
  const int tid = threadIdx.x, b = blockIdx.x;
  const int lane = tid & 63, wid = tid >> 6;
  sscat[tid] = -1;
  __syncthreads();
  for (int g = tid; g < M_SZ; g += 256) {
    u64 key = gkey[g];
    int pidx = (int)(0xFFFFFFFFu - (u32)key);  // low32 decode unaffected by COL_TAG
    if ((pidx >> 8) == b) atomicMax(&sscat[pidx & 255], g);  // dup idx_g: last (max g) wins
  }
  __syncthreads();
  const int i = (b << 8) + tid;
  u64 rk = rowkey[i];
  float best = __uint_as_float((u32)(rk >> 32));
  int idxp = (int)(0xFFFFFFFFu - (u32)rk);
  int m;
  if (best < F_LOWER) m = -2;
  else {
    int s = sscat[tid];
    m = (s >= 0) ? s : ((best >= F_UPPER) ? idxp : -1);
  }
  matches[i] = m;
  u32 ub = threefry_bits((u32)i, L_SZ >> 1) >> 9;
  neg_u[i] = (m == -2) ? ub : 0xFFFFFFFFu;
  float ce = 0.0f;
  if (m >= 0) {
    ce = lse[i] - scores[(size_t)i * C_SZ + gtc[m]];
  } else if (m == -2) {
    u32 bin = ub >> 10;
    u32 pos = atomicAdd(&hist0[bin], 1u);          // spread over 8192 bins
    if (pos < BIN_CAP) bins[(size_t)bin * BIN_CAP + pos] = ((u64)ub << 16) | (u32)i;
  }
  u64 balp = __ballot(m >= 0);
  u64 baln = __ballot(m == -2);
  double acc = (double)ce;
  for (int off = 32; off > 0; off >>= 1) acc += __shfl_down(acc, off, 64);
  if (lane == 0) { swsum[wid] = __popcll(balp); sncnt[wid] = __popcll(baln); sdacc[wid] = acc; }
  __syncthreads();
  if (tid == 0) {
    u32 cp = (u32)(swsum[0] + swsum[1] + swsum[2] + swsum[3]);
    u32 cn = (u32)(sncnt[0] + sncnt[1] + sncnt[2] + sncnt[3]);
    blockcnt[b] = cp | (cn << 16);
    posce[b] = sdacc[0] + sdacc[1] + sdacc[2] + sdacc[3];
  }
}

// ======== kB2: blockcnt scan + compaction + REDUNDANT per-block selection + neg-CE
// partials; block 255 initializes State. 256 blocks. All inputs boundary-visible.
__global__ void __launch_bounds__(256) kB2(const int* __restrict__ matches,
    const float4* __restrict__ pred, const float4* __restrict__ gtb,
    const u32* __restrict__ blockcnt, float4* __restrict__ pp, float4* __restrict__ gp,
    const u32* __restrict__ hist0, const u64* __restrict__ bins,
    const u32* __restrict__ neg_u, const float* __restrict__ scores,
    const float* __restrict__ lse, double* __restrict__ negce, State* st) {
  __shared__ int sscan[256];
  __shared__ int swsum[4], sncnt[4];
  __shared__ double sdacc[4];
  __shared__ int s_d, s_kk, s_cnt;
  __shared__ u32 s_ovf;
  __shared__ u64 sth;
  __shared__ u64 scand[OVF_CAP];
  const int tid = threadIdx.x, b = blockIdx.x;
  const int lane = tid & 63, wid = tid >> 6;
  u32 v = blockcnt[tid];
  int cp = (int)(v & 0xFFFFu), cn = (int)(v >> 16);
  sscan[tid] = cp;
  {
    int c = cn;
    for (int off = 32; off > 0; off >>= 1) c += __shfl_down(c, off, 64);
    if (lane == 0) sncnt[wid] = c;
  }
  __syncthreads();
  for (int off = 1; off < 256; off <<= 1) {
    int x = (tid >= off) ? sscan[tid - off] : 0;
    __syncthreads();
    sscan[tid] += x;
    __syncthreads();
  }
  const int bpref = (b == 0) ? 0 : sscan[b - 1];
  const int np = sscan[255];
  const int nn = sncnt[0] + sncnt[1] + sncnt[2] + sncnt[3];
  const int i = (b << 8) + tid;
  const int m = matches[i];
  if (bpref < MAX_POS) {  // block-uniform
    int flag = (m >= 0) ? 1 : 0;
    int incl = flag;
#pragma unroll
    for (int off = 1; off < 64; off <<= 1) {
      int x = __shfl_up(incl, off, 64);
      if (lane >= off) incl += x;
    }
    if (lane == 63) swsum[wid] = incl;
    __syncthreads();
    int wbase = 0;
    for (int w = 0; w < wid; ++w) wbase += swsum[w];
    int rank = bpref + wbase + incl - flag;
    if (flag && rank < MAX_POS) { pp[rank] = pred[i]; gp[rank] = gtb[m]; }
  }
  __syncthreads();
  // redundant negative selection (every block; ~32KB L2-hot hist + <=32-cand rank select)
  u64 thresh = ~0ull;  // np >= nn -> all negatives selected (bg_num = round(np*1.0) = np)
  if (np < nn) {
    const uint4* h4 = (const uint4*)hist0;
    u32 loc[32]; int tsum = 0;
#pragma unroll
    for (int r = 0; r < 8; ++r) {
      uint4 hv = h4[tid * 8 + r];
      loc[r*4] = hv.x; loc[r*4+1] = hv.y; loc[r*4+2] = hv.z; loc[r*4+3] = hv.w;
      tsum += (int)(hv.x + hv.y + hv.z + hv.w);
    }
    sscan[tid] = tsum;
    __syncthreads();
    for (int off = 1; off < 256; off <<= 1) {
      int x = (tid >= off) ? sscan[tid - off] : 0;
      __syncthreads();
      sscan[tid] += x;
      __syncthreads();
    }
    int incl2 = sscan[tid], excl2 = incl2 - tsum;
    if (np >= excl2 && np < incl2) {
      int kk = np - excl2; int d = 0, c = 0;
#pragma unroll
      for (int r = 0; r < 32; ++r) {
        if (kk < (int)loc[r]) { d = tid * 32 + r; c = (int)loc[r]; break; }
        kk -= (int)loc[r];
      }
      s_d = d; s_kk = kk; s_cnt = c;
    }
    if (tid == 0) s_ovf = 0;
    __syncthreads();
    const int d = s_d, kk = s_kk, cnt = s_cnt;
    if (cnt <= BIN_CAP) {
      if (tid < cnt) scand[tid] = bins[(size_t)d * BIN_CAP + tid];
      __syncthreads();
      if (tid < cnt) {
        u64 key = scand[tid];
        int rank = 0;
        for (int u = 0; u < cnt; ++u) rank += (scand[u] < key) ? 1 : 0;
        if (rank == kk) sth = key;  // keys unique -> single writer
      }
    } else {
      // fallback (Poisson(8) > 32: ~1e-12 per bin): sweep neg_u for bin-d keys
      for (int t = tid; t < L_SZ; t += 256) {
        u32 u = neg_u[t];
        if (u != 0xFFFFFFFFu && (int)(u >> 10) == d) {
          u32 pos = atomicAdd(&s_ovf, 1u);
          if (pos < OVF_CAP) scand[pos] = ((u64)u << 16) | (u32)t;
        }
      }
      __syncthreads();
      int c2 = (int)s_ovf; if (c2 > OVF_CAP) c2 = OVF_CAP;
      for (int t = tid; t < c2; t += 256) {
        u64 key = scand[t];
        int rank = 0;
        for (int u = 0; u < c2; ++u) rank += (scand[u] < key) ? 1 : 0;
        if (rank == kk) sth = key;
      }
    }
    __syncthreads();
    thresh = sth;  // select keys strictly below the rank-bg_num key
  }
  double acc = 0.0;
  if (m == -2) {
    u32 u = neg_u[i];
    u64 key = ((u64)u << 16) | (u32)i;
    if (key < thresh)
      acc = (double)(lse[i] - scores[(size_t)i * C_SZ + (C_SZ - 1)]);  // BACKGROUND=20
  }
  for (int off = 32; off > 0; off >>= 1) acc += __shfl_down(acc, off, 64);
  if (lane == 0) sdacc[wid] = acc;
  __syncthreads();
  if (tid == 0) {
    negce[b] = sdacc[0] + sdacc[1] + sdacc[2] + sdacc[3];
    if (b == 255) {  // initialize State for kC (0xAA-poisoned otherwise)
      st->num_pos = np; st->num_neg = nn;
      st->done = 0; st->bbox_sum = 0.0;
    }
  }
}

// ======== kC: pair smooth-L1 (128 blocks = 8 i-tiles x 16 j-tiles) + last-block final.
__global__ void __launch_bounds__(256) kC(const float4* __restrict__ pp,
    const float4* __restrict__ gp, const double* __restrict__ posce,
    const double* __restrict__ negce, State* st, float* __restrict__ out) {
  __shared__ float4 sj[128];
  __shared__ double sdacc[4];
  __shared__ int s_last;
  const int tid = threadIdx.x, b = blockIdx.x;
  const int lane = tid & 63, wid = tid >> 6;
  int n = st->num_pos; if (n > MAX_POS) n = MAX_POS;
  const int jb = (b & 15) << 7;
  if (tid < 128) {
    int j = jb + tid;
    sj[tid] = (j < n) ? pp[j] : make_float4(0.f, 0.f, 0.f, 0.f);
  }
  __syncthreads();
  const int ii = ((b >> 4) << 8) + tid;
  double pacc = 0.0;
  if (ii < n) {
    float4 g = gp[ii];
    int jend = n - jb; if (jend > 128) jend = 128;
    for (int j = 0; j < jend; ++j) {
      float4 p4 = sj[j];
      pacc += (double)sl1(p4.x - g.x);
      pacc += (double)sl1(p4.y - g.y);
      pacc += (double)sl1(p4.z - g.z);
      pacc += (double)sl1(p4.w - g.w);
    }
  }
  for (int off = 32; off > 0; off >>= 1) pacc += __shfl_down(pacc, off, 64);
  if (lane == 0) sdacc[wid] = pacc;
  __syncthreads();
  if (tid == 0) {
    atomicAdd(&st->bbox_sum, sdacc[0] + sdacc[1] + sdacc[2] + sdacc[3]);
    __threadfence();
    u32 dn = atomicAdd(&st->done, 1u);
    s_last = (dn == 127) ? 1 : 0;
  }
  __syncthreads();
  if (!s_last) return;
  double a = posce[tid] + negce[tid];
  for (int off = 32; off > 0; off >>= 1) a += __shfl_down(a, off, 64);
  if (lane == 0) sdacc[wid] = a;
  __syncthreads();
  if (tid == 0) {
    double ce = sdacc[0] + sdacc[1] + sdacc[2] + sdacc[3];
    double bbs = __hip_atomic_load(&st->bbox_sum, __ATOMIC_ACQUIRE, __HIP_MEMORY_SCOPE_AGENT);
    int np = st->num_pos, nn = st->num_neg;
    int nsel = (np < nn) ? np : nn;
    double wsum = (double)(np + nsel);
    out[0] = (float)(ce / wsum);
    out[1] = (float)bbs;
  }
}

// ---------- launch ----------

extern "C" void kernel_launch(void* const* d_in, const int* in_sizes, int n_in,
                              void* d_out, int out_size, void* d_ws, size_t ws_size,
                              hipStream_t stream) {
  const float* rois   = (const float*)d_in[0];
  const float* scores = (const float*)d_in[1];
  const float* deltas = (const float*)d_in[2];
  const float4* gtb   = (const float4*)d_in[3];
  const int*   gtc    = (const int*)d_in[4];
  float* out = (float*)d_out;

  char* w = (char*)d_ws;
  // NO memset: gkey uses COL_TAG so poison always loses under atomicMax (idempotent on
  // stale reruns); hist0 zeroed inside kA; everything else is written before read.
  State* st    = (State*)w;   w += 256;
  u64* gkey    = (u64*)w;     w += (size_t)M_SZ * 8;
  u32* hist0   = (u32*)w;     w += (size_t)NBINS * 4;
  u64* bins    = (u64*)w;     w += (size_t)NBINS * BIN_CAP * 8;
  float4* pred = (float4*)w;  w += (size_t)L_SZ * 16;
  float* lse   = (float*)w;   w += (size_t)L_SZ * 4;
  u64* rowkey  = (u64*)w;     w += (size_t)L_SZ * 8;
  int* matches = (int*)w;     w += (size_t)L_SZ * 4;
  u32* neg_u   = (u32*)w;     w += (size_t)L_SZ * 4;
  float4* pp   = (float4*)w;  w += (size_t)MAX_POS * 16;
  float4* gp   = (float4*)w;  w += (size_t)MAX_POS * 16;
  u32* blockcnt= (u32*)w;     w += 256 * 4;
  double* posce= (double*)w;  w += 256 * 8;
  double* negce= (double*)w;  w += 256 * 8;

  kA<<<L_SZ / 64, 256, 0, stream>>>(rois, scores, deltas, gtb, pred, lse, rowkey, gkey, hist0);
  kB1<<<L_SZ / 256, 256, 0, stream>>>(rowkey, gkey, gtc, scores, lse, matches, neg_u,
                                      hist0, bins, blockcnt, posce);
  kB2<<<L_SZ / 256, 256, 0, stream>>>(matches, pred, gtb, blockcnt, pp, gp,
                                      hist0, bins, neg_u, scores, lse, negce, st);
  kC<<<128, 256, 0, stream>>>(pp, gp, posce, negce, st, out);
}

// Round 15
// 131.866 us; speedup vs baseline: 3.2996x; 1.0090x over previous
//
#include <hip/hip_runtime.h>
#include <stdint.h>

typedef unsigned int u32;
typedef unsigned long long u64;

#define F_UPPER 0.4f
#define F_LOWER 0.1f
#define MAX_POS 2048
#define L_SZ 65536
#define M_SZ 512
#define C_SZ 21
#define NBINS 8192
#define BIN_CAP 32
#define OVF_CAP 1024
// High-bit tag so any valid column key beats the harness 0xAA poison pattern under
// unsigned atomicMax (0xAAAA.. < 0xC000..). Valid keys have iou float bits < 0x4000_0000,
// so OR-ing the tag is an order-preserving +constant. Low 32 bits (pred idx) untouched.
#define COL_TAG 0xC000000000000000ull

struct State {
  int num_pos;
  int num_neg;
  u32 done;
  u32 _pad;
  double bbox_sum;
};

__device__ __forceinline__ float area_fn(const float4 a) {
#pragma clang fp contract(off)
  return (a.z - a.x + 1.0f) * (a.w - a.y + 1.0f);
}

// IoU, op order identical to prior rounds (absmax 0 preserved).
__device__ __forceinline__ float iou_rcp(const float4 a, const float4 b, float a1, float a2) {
#pragma clang fp contract(off)
  float iw = fminf(a.z, b.z) - fmaxf(a.x, b.x) + 1.0f;
  iw = fmaxf(iw, 0.0f);
  float ih = fminf(a.w, b.w) - fmaxf(a.y, b.y) + 1.0f;
  ih = fmaxf(ih, 0.0f);
  float inter = iw * ih;
  return inter * __builtin_amdgcn_rcpf(a1 + a2 - inter);
}

__device__ __forceinline__ float sl1(float d) {
#pragma clang fp contract(off)
  float ad = fabsf(d);
  return (ad < 0.01f) ? (50.0f * d * d) : (ad - 0.005f);
}

__device__ __forceinline__ u32 rotl(u32 x, int d) { return (x << d) | (x >> (32 - d)); }

// JAX threefry2x32, key=(0,42); counts = iota(L) split in halves.
__device__ u32 threefry_bits(u32 i, u32 H) {
  u32 x0, x1; bool hi;
  if (i < H) { x0 = i;     x1 = i + H; hi = false; }
  else       { x0 = i - H; x1 = i;     hi = true;  }
  const u32 ks0 = 0u, ks1 = 42u;
  const u32 ks2 = ks0 ^ ks1 ^ 0x1BD11BDAu;
  x0 += ks0; x1 += ks1;
#define RND(r) { x0 += x1; x1 = rotl(x1, r); x1 ^= x0; }
  RND(13) RND(15) RND(26) RND(6)   x0 += ks1; x1 += ks2 + 1u;
  RND(17) RND(29) RND(16) RND(24)  x0 += ks2; x1 += ks0 + 2u;
  RND(13) RND(15) RND(26) RND(6)   x0 += ks0; x1 += ks1 + 3u;
  RND(17) RND(29) RND(16) RND(24)  x0 += ks1; x1 += ks2 + 4u;
  RND(13) RND(15) RND(26) RND(6)   x0 += ks2; x1 += ks0 + 5u;
#undef RND
  return hi ? x1 : x0;
}

// ======== kA: ROI + single-pass register-microtiled IoU + hist0 zeroing.
// 1024 blocks, 64 preds/block. pg=tid&7 owns 8 preds (VGPRs); gg=tid>>3 owns 16 gts.
// Float-compare argmax tracking; col merge skips IoU==0 (kills same-address atomic chains).
__global__ void __launch_bounds__(256) kA(const float* __restrict__ rois,
    const float* __restrict__ scores, const float* __restrict__ deltas,
    const float4* __restrict__ gtb,
    float4* __restrict__ pred, float* __restrict__ lse,
    u64* __restrict__ rowkey, u64* __restrict__ gkey, u32* __restrict__ hist0) {
  __shared__ float  ssc[64 * C_SZ];
  __shared__ float  sro[64 * 5];
  __shared__ float4 sg[M_SZ];
  __shared__ float  ga[M_SZ];
  __shared__ u64    scol[M_SZ];
  __shared__ u64    srow[64];
  __shared__ float4 spred[64];
  __shared__ float  sarea[64];
  const int tid = threadIdx.x;
  const int pbase = blockIdx.x << 6;
  if (tid < 8) hist0[(blockIdx.x << 3) + tid] = 0u;  // 1024 blocks x 8 = 8192 entries
  for (int k = tid; k < 64 * C_SZ; k += 256) ssc[k] = scores[(size_t)pbase * C_SZ + k];
  for (int k = tid; k < 64 * 5; k += 256)    sro[k] = rois[(size_t)pbase * 5 + k];
  for (int j = tid; j < M_SZ; j += 256) {
    float4 g = gtb[j]; sg[j] = g; ga[j] = area_fn(g); scol[j] = 0ull;
  }
  if (tid < 64) srow[tid] = 0ull;
  __syncthreads();
  if (tid < 64) {
    const int i = pbase + tid;
    const float* sr = ssc + tid * C_SZ;
    float mx = sr[0]; int mi = 0;
    for (int j = 1; j < C_SZ; ++j) { float v = sr[j]; if (v > mx) { mx = v; mi = j; } }
    float s = 0.0f;
    for (int j = 0; j < C_SZ; ++j) s += expf(sr[j] - mx);
    lse[i] = mx + logf(s);
    // 16B-aligned gather: (84*i + 4*mi) floats is a multiple of 4 floats.
    float4 d = *(const float4*)(deltas + (size_t)i * (4 * C_SZ) + 4 * mi);
    const float* r = sro + tid * 5;
    float4 pb;
    pb.x = r[1] + d.x; pb.y = r[2] + d.y; pb.z = r[3] + d.z; pb.w = r[4] + d.w;
    spred[tid] = pb; sarea[tid] = area_fn(pb);
    pred[i] = pb;
  }
  __syncthreads();
  const int pg = tid & 7;
  const int gg = tid >> 3;
  const int p0 = pg << 3;
  float4 pb[8]; float pa[8]; float rbest[8]; int rbj[8];
#pragma unroll
  for (int r = 0; r < 8; ++r) {
    pb[r] = spred[p0 + r];
    pa[r] = sarea[p0 + r];
    rbest[r] = -1.0f;  // first eval (v>=0) always replaces
    rbj[r] = 0;
  }
  const int jbase = gg << 4;
  const int joff = pg << 1;  // 8 same-gg threads -> distinct j each iter (no atomic collisions)
#pragma unroll 2
  for (int jj = 0; jj < 16; ++jj) {
    const int j = jbase + ((jj + joff) & 15);
    const float4 gb = sg[j];
    const float gba = ga[j];
    float cbest = 0.0f; int cbp = 0;
#pragma unroll
    for (int r = 0; r < 8; ++r) {
      float v = iou_rcp(pb[r], gb, pa[r], gba);
      if (v > rbest[r]) { rbest[r] = v; rbj[r] = j; }  // row max (ties measure-zero)
      if (v > cbest) { cbest = v; cbp = r; }           // col max among owned preds
    }
    if (cbest > 0.0f) {  // zero-IoU columns can't define a consumed argmax; skip merge
      u64 c = ((u64)__float_as_uint(cbest) << 32) |
              (u32)(0xFFFFFFFFu - (u32)(pbase + p0 + cbp));
      atomicMax(&scol[j], c);
    }
  }
#pragma unroll
  for (int r = 0; r < 8; ++r) {
    u64 k = ((u64)__float_as_uint(rbest[r]) << 32) | (u32)(0xFFFFFFFFu - (u32)rbj[r]);
    atomicMax(&srow[p0 + r], k);
  }
  __syncthreads();
  if (tid < 64) rowkey[pbase + tid] = srow[tid];
  // Global col merge: only blocks with a positive-IoU local max write (few per gt).
  for (int j = tid; j < M_SZ; j += 256) {
    u64 c = scol[j];
    if ((c >> 32) != 0ull) atomicMax(&gkey[j], c | COL_TAG);
  }
}

// ======== kB1: scat + match + pos-CE partial + bucket-store + per-block counts
// + LOCAL compaction staging (intra-block rank -> ppg/gpg). 256 blocks.
// Zero cross-block communication; visibility via kernel boundary.
__global__ void __launch_bounds__(256) kB1(const u64* __restrict__ rowkey,
    const u64* __restrict__ gkey, const int* __restrict__ gtc,
    const float* __restrict__ scores, const float* __restrict__ lse,
    const float4* __restrict__ pred, const float4* __restrict__ gtb,
    u32* __restrict__ neg_u, u32* __restrict__ hist0, u64* __restrict__ bins,
    u32* __restrict__ blockcnt, double* __restrict__ posce,
    float4* __restrict__ ppg, float4* __restrict__ gpg) {
  __shared__ int sscat[256];
  __shared__ int swsum[4], sncnt[4];
  __shared__ double sdacc[4];
  const int tid = threadIdx.x, b = blockIdx.x;
  const int lane = tid & 63, wid = tid >> 6;
  sscat[tid] = -1;
  __syncthreads();
  for (int g = tid; g < M_SZ; g += 256) {
    u64 key = gkey[g];
    int pidx = (int)(0xFFFFFFFFu - (u32)key);  // low32 decode unaffected by COL_TAG
    if ((pidx >> 8) == b) atomicMax(&sscat[pidx & 255], g);  // dup idx_g: last (max g) wins
  }
  __syncthreads();
  const int i = (b << 8) + tid;
  u64 rk = rowkey[i];
  float best = __uint_as_float((u32)(rk >> 32));
  int idxp = (int)(0xFFFFFFFFu - (u32)rk);
  int m;
  if (best < F_LOWER) m = -2;
  else {
    int s = sscat[tid];
    m = (s >= 0) ? s : ((best >= F_UPPER) ? idxp : -1);
  }
  u32 ub = threefry_bits((u32)i, L_SZ >> 1) >> 9;
  neg_u[i] = (m == -2) ? ub : 0xFFFFFFFFu;
  float ce = 0.0f;
  if (m >= 0) {
    ce = lse[i] - scores[(size_t)i * C_SZ + gtc[m]];
  } else if (m == -2) {
    u32 bin = ub >> 10;
    u32 pos = atomicAdd(&hist0[bin], 1u);          // spread over 8192 bins
    if (pos < BIN_CAP) bins[(size_t)bin * BIN_CAP + pos] = ((u64)ub << 16) | (u32)i;
  }
  // intra-block index-ordered rank for positives + counts (one scan pass)
  const int flag = (m >= 0) ? 1 : 0;
  int incl = flag;
#pragma unroll
  for (int off = 1; off < 64; off <<= 1) {
    int x = __shfl_up(incl, off, 64);
    if (lane >= off) incl += x;
  }
  u64 baln = __ballot(m == -2);
  double acc = (double)ce;
  for (int off = 32; off > 0; off >>= 1) acc += __shfl_down(acc, off, 64);
  if (lane == 63) swsum[wid] = incl;
  if (lane == 0) { sncnt[wid] = __popcll(baln); sdacc[wid] = acc; }
  __syncthreads();
  int wbase = 0;
  for (int w = 0; w < wid; ++w) wbase += swsum[w];
  if (flag) {
    int lrank = wbase + incl - flag;  // local index-ordered rank, < 256
    ppg[(b << 8) + lrank] = pred[i];
    gpg[(b << 8) + lrank] = gtb[m];
  }
  if (tid == 0) {
    u32 cp = (u32)(swsum[0] + swsum[1] + swsum[2] + swsum[3]);
    u32 cn = (u32)(sncnt[0] + sncnt[1] + sncnt[2] + sncnt[3]);
    blockcnt[b] = cp | (cn << 16);
    posce[b] = sdacc[0] + sdacc[1] + sdacc[2] + sdacc[3];
  }
}

// ======== kB2: blockcnt scan + dense staged copy + REDUNDANT per-block selection +
// neg-CE partials; block 255 initializes State. 256 blocks. All inputs boundary-visible.
__global__ void __launch_bounds__(256) kB2(const float4* __restrict__ ppg,
    const float4* __restrict__ gpg,
    const u32* __restrict__ blockcnt, float4* __restrict__ pp, float4* __restrict__ gp,
    const u32* __restrict__ hist0, const u64* __restrict__ bins,
    const u32* __restrict__ neg_u, const float* __restrict__ scores,
    const float* __restrict__ lse, double* __restrict__ negce, State* st) {
  __shared__ int sscan[256];
  __shared__ int sncnt[4];
  __shared__ double sdacc[4];
  __shared__ int s_d, s_kk, s_cnt;
  __shared__ u32 s_ovf;
  __shared__ u64 sth;
  __shared__ u64 scand[OVF_CAP];
  const int tid = threadIdx.x, b = blockIdx.x;
  const int lane = tid & 63, wid = tid >> 6;
  u32 v = blockcnt[tid];
  int cp = (int)(v & 0xFFFFu), cn = (int)(v >> 16);
  sscan[tid] = cp;
  {
    int c = cn;
    for (int off = 32; off > 0; off >>= 1) c += __shfl_down(c, off, 64);
    if (lane == 0) sncnt[wid] = c;
  }
  __syncthreads();
  const int cnt_b = sscan[b];  // this block's positive count (pre-scan value)
  for (int off = 1; off < 256; off <<= 1) {
    int x = (tid >= off) ? sscan[tid - off] : 0;
    __syncthreads();
    sscan[tid] += x;
    __syncthreads();
  }
  const int bpref = (b == 0) ? 0 : sscan[b - 1];
  const int np = sscan[255];
  const int nn = sncnt[0] + sncnt[1] + sncnt[2] + sncnt[3];
  // dense staged copy: global rank = bpref + local rank (index order preserved)
  if (tid < cnt_b) {
    int rank = bpref + tid;
    if (rank < MAX_POS) {
      pp[rank] = ppg[(b << 8) + tid];
      gp[rank] = gpg[(b << 8) + tid];
    }
  }
  __syncthreads();
  // redundant negative selection (every block; ~32KB L2-hot hist + <=32-cand rank select)
  u64 thresh = ~0ull;  // np >= nn -> all negatives selected (bg_num = round(np*1.0) = np)
  if (np < nn) {
    const uint4* h4 = (const uint4*)hist0;
    u32 loc[32]; int tsum = 0;
#pragma unroll
    for (int r = 0; r < 8; ++r) {
      uint4 hv = h4[tid * 8 + r];
      loc[r*4] = hv.x; loc[r*4+1] = hv.y; loc[r*4+2] = hv.z; loc[r*4+3] = hv.w;
      tsum += (int)(hv.x + hv.y + hv.z + hv.w);
    }
    sscan[tid] = tsum;
    __syncthreads();
    for (int off = 1; off < 256; off <<= 1) {
      int x = (tid >= off) ? sscan[tid - off] : 0;
      __syncthreads();
      sscan[tid] += x;
      __syncthreads();
    }
    int incl2 = sscan[tid], excl2 = incl2 - tsum;
    if (np >= excl2 && np < incl2) {
      int kk = np - excl2; int d = 0, c = 0;
#pragma unroll
      for (int r = 0; r < 32; ++r) {
        if (kk < (int)loc[r]) { d = tid * 32 + r; c = (int)loc[r]; break; }
        kk -= (int)loc[r];
      }
      s_d = d; s_kk = kk; s_cnt = c;
    }
    if (tid == 0) s_ovf = 0;
    __syncthreads();
    const int d = s_d, kk = s_kk, cnt = s_cnt;
    if (cnt <= BIN_CAP) {
      if (tid < cnt) scand[tid] = bins[(size_t)d * BIN_CAP + tid];
      __syncthreads();
      if (tid < cnt) {
        u64 key = scand[tid];
        int rank = 0;
        for (int u = 0; u < cnt; ++u) rank += (scand[u] < key) ? 1 : 0;
        if (rank == kk) sth = key;  // keys unique -> single writer
      }
    } else {
      // fallback (Poisson(8) > 32: ~1e-12 per bin): sweep neg_u for bin-d keys
      for (int t = tid; t < L_SZ; t += 256) {
        u32 u = neg_u[t];
        if (u != 0xFFFFFFFFu && (int)(u >> 10) == d) {
          u32 pos = atomicAdd(&s_ovf, 1u);
          if (pos < OVF_CAP) scand[pos] = ((u64)u << 16) | (u32)t;
        }
      }
      __syncthreads();
      int c2 = (int)s_ovf; if (c2 > OVF_CAP) c2 = OVF_CAP;
      for (int t = tid; t < c2; t += 256) {
        u64 key = scand[t];
        int rank = 0;
        for (int u = 0; u < c2; ++u) rank += (scand[u] < key) ? 1 : 0;
        if (rank == kk) sth = key;
      }
    }
    __syncthreads();
    thresh = sth;  // select keys strictly below the rank-bg_num key
  }
  // negative CE partial for own range (negativity <=> neg_u[i] != sentinel)
  const int i = (b << 8) + tid;
  u32 u = neg_u[i];
  double acc = 0.0;
  if (u != 0xFFFFFFFFu) {
    u64 key = ((u64)u << 16) | (u32)i;
    if (key < thresh)
      acc = (double)(lse[i] - scores[(size_t)i * C_SZ + (C_SZ - 1)]);  // BACKGROUND=20
  }
  for (int off = 32; off > 0; off >>= 1) acc += __shfl_down(acc, off, 64);
  if (lane == 0) sdacc[wid] = acc;
  __syncthreads();
  if (tid == 0) {
    negce[b] = sdacc[0] + sdacc[1] + sdacc[2] + sdacc[3];
    if (b == 255) {  // initialize State for kC (0xAA-poisoned otherwise)
      st->num_pos = np; st->num_neg = nn;
      st->done = 0; st->bbox_sum = 0.0;
    }
  }
}

// ======== kC: pair smooth-L1 (128 blocks = 8 i-tiles x 16 j-tiles) + last-block final.
__global__ void __launch_bounds__(256) kC(const float4* __restrict__ pp,
    const float4* __restrict__ gp, const double* __restrict__ posce,
    const double* __restrict__ negce, State* st, float* __restrict__ out) {
  __shared__ float4 sj[128];
  __shared__ double sdacc[4];
  __shared__ int s_last;
  const int tid = threadIdx.x, b = blockIdx.x;
  const int lane = tid & 63, wid = tid >> 6;
  int n = st->num_pos; if (n > MAX_POS) n = MAX_POS;
  const int jb = (b & 15) << 7;
  if (tid < 128) {
    int j = jb + tid;
    sj[tid] = (j < n) ? pp[j] : make_float4(0.f, 0.f, 0.f, 0.f);
  }
  __syncthreads();
  const int ii = ((b >> 4) << 8) + tid;
  double pacc = 0.0;
  if (ii < n) {
    float4 g = gp[ii];
    int jend = n - jb; if (jend > 128) jend = 128;
    for (int j = 0; j < jend; ++j) {
      float4 p4 = sj[j];
      pacc += (double)sl1(p4.x - g.x);
      pacc += (double)sl1(p4.y - g.y);
      pacc += (double)sl1(p4.z - g.z);
      pacc += (double)sl1(p4.w - g.w);
    }
  }
  for (int off = 32; off > 0; off >>= 1) pacc += __shfl_down(pacc, off, 64);
  if (lane == 0) sdacc[wid] = pacc;
  __syncthreads();
  if (tid == 0) {
    atomicAdd(&st->bbox_sum, sdacc[0] + sdacc[1] + sdacc[2] + sdacc[3]);
    __threadfence();
    u32 dn = atomicAdd(&st->done, 1u);
    s_last = (dn == 127) ? 1 : 0;
  }
  __syncthreads();
  if (!s_last) return;
  double a = posce[tid] + negce[tid];
  for (int off = 32; off > 0; off >>= 1) a += __shfl_down(a, off, 64);
  if (lane == 0) sdacc[wid] = a;
  __syncthreads();
  if (tid == 0) {
    double ce = sdacc[0] + sdacc[1] + sdacc[2] + sdacc[3];
    double bbs = __hip_atomic_load(&st->bbox_sum, __ATOMIC_ACQUIRE, __HIP_MEMORY_SCOPE_AGENT);
    int np = st->num_pos, nn = st->num_neg;
    int nsel = (np < nn) ? np : nn;
    double wsum = (double)(np + nsel);
    out[0] = (float)(ce / wsum);
    out[1] = (float)bbs;
  }
}

// ---------- launch ----------

extern "C" void kernel_launch(void* const* d_in, const int* in_sizes, int n_in,
                              void* d_out, int out_size, void* d_ws, size_t ws_size,
                              hipStream_t stream) {
  const float* rois   = (const float*)d_in[0];
  const float* scores = (const float*)d_in[1];
  const float* deltas = (const float*)d_in[2];
  const float4* gtb   = (const float4*)d_in[3];
  const int*   gtc    = (const int*)d_in[4];
  float* out = (float*)d_out;

  char* w = (char*)d_ws;
  // NO memset: gkey uses COL_TAG so poison always loses under atomicMax (idempotent on
  // stale reruns); hist0 zeroed inside kA; everything else is written before read.
  State* st    = (State*)w;   w += 256;
  u64* gkey    = (u64*)w;     w += (size_t)M_SZ * 8;
  u32* hist0   = (u32*)w;     w += (size_t)NBINS * 4;
  u64* bins    = (u64*)w;     w += (size_t)NBINS * BIN_CAP * 8;
  float4* pred = (float4*)w;  w += (size_t)L_SZ * 16;
  float* lse   = (float*)w;   w += (size_t)L_SZ * 4;
  u64* rowkey  = (u64*)w;     w += (size_t)L_SZ * 8;
  u32* neg_u   = (u32*)w;     w += (size_t)L_SZ * 4;
  float4* ppg  = (float4*)w;  w += (size_t)256 * 256 * 16;  // per-block staged pred
  float4* gpg  = (float4*)w;  w += (size_t)256 * 256 * 16;  // per-block staged gt
  float4* pp   = (float4*)w;  w += (size_t)MAX_POS * 16;
  float4* gp   = (float4*)w;  w += (size_t)MAX_POS * 16;
  u32* blockcnt= (u32*)w;     w += 256 * 4;
  double* posce= (double*)w;  w += 256 * 8;
  double* negce= (double*)w;  w += 256 * 8;

  kA<<<L_SZ / 64, 256, 0, stream>>>(rois, scores, deltas, gtb, pred, lse, rowkey, gkey, hist0);
  kB1<<<L_SZ / 256, 256, 0, stream>>>(rowkey, gkey, gtc, scores, lse, pred, gtb,
                                      neg_u, hist0, bins, blockcnt, posce, ppg, gpg);
  kB2<<<L_SZ / 256, 256, 0, stream>>>(ppg, gpg, blockcnt, pp, gp,
                                      hist0, bins, neg_u, scores, lse, negce, st);
  kC<<<128, 256, 0, stream>>>(pp, gp, posce, negce, st, out);
}